// Round 4
// baseline (256.079 us; speedup 1.0000x reference)
//
#include <hip/hip_runtime.h>
#include <hip/hip_bf16.h>

// ---------------- problem constants ----------------
#define QN 1024
#define NDB 200000
#define NDB_PAD 200064        // 3126 subtiles of 64 rows
#define PDBW 257
#define CDIM 256
#define TK 16
#define NEGF (-1e30f)
#define MIN_SIM_C 0.05f
#define MIN_VOTES_C 0.3f

// fast path: 64 chunks x 4 query-tiles (256 q/block); survivor filter
#define NCH 64
#define THETA 0.19f           // P(sim>THETA)=1.18e-3; true 16th-best ~0.236
#define CAPQ 20               // per-(query,chunk) cap (lambda=3.7, P(over)~4e-10)
// fallback (round-1, proven) path
#define NCHUNK1 49
#define CPQ1 (NCHUNK1*32)

typedef __attribute__((ext_vector_type(8))) short bf16x8;
typedef __attribute__((ext_vector_type(4))) float f32x4;

__device__ __forceinline__ short f2bf(float f) {
  union { float f; unsigned u; } x; x.f = f;
  unsigned u = x.u;
  return (short)((u + 0x7fffu + ((u >> 16) & 1u)) >> 16);  // RNE
}

__device__ __forceinline__ void async_copy16(const void* gp, void* lp) {
  __builtin_amdgcn_global_load_lds(
      (__attribute__((address_space(1))) void*)gp,
      (__attribute__((address_space(3))) void*)lp, 16, 0, 0);
}

// ---------------------------------------------------------------------------
// Kernel 0: pdb fp32 -> bf16, row-swizzled (16B block e -> e^(r&7)), zero-pad.
// ---------------------------------------------------------------------------
__global__ __launch_bounds__(256) void convert_db_kernel(
    const float* __restrict__ pdb, unsigned long long* __restrict__ dbb)
{
  const int wv = (int)threadIdx.x >> 6, lane = (int)threadIdx.x & 63;
  for (int r = (int)blockIdx.x*4 + wv; r < NDB_PAD; r += (int)gridDim.x*4) {
    const int c  = lane << 2;
    const int cs = c ^ ((r & 7) << 3);
    unsigned long long pack = 0ull;
    if (r < NDB) {
      const float* p = pdb + (size_t)r*PDBW + c;
      unsigned long long b0 = (unsigned short)f2bf(p[0]);
      unsigned long long b1 = (unsigned short)f2bf(p[1]);
      unsigned long long b2 = (unsigned short)f2bf(p[2]);
      unsigned long long b3 = (unsigned short)f2bf(p[3]);
      pack = b0 | (b1 << 16) | (b2 << 32) | (b3 << 48);
    }
    *(unsigned long long*)((char*)dbb + (size_t)r*512 + (cs << 1)) = pack;
  }
}

// ---------------------------------------------------------------------------
// Kernel 1: MFMA sims + register theta-filter + LDS survivor append.
// grid (64, 4), 256 thr (4 waves x 64 queries, fm=4). Subtile = 64 db rows.
// Double-buffered LDS + counted vmcnt(8) + raw barriers (loads in flight
// across barriers). Survivor appends are LDS-atomic (lgkm domain — never
// drains the vmem prefetch queue). 107.5KB LDS -> 1 block/CU, 1 wave/SIMD.
// ---------------------------------------------------------------------------
__global__ __launch_bounds__(256, 1) void sims_filter_kernel(
    const float* __restrict__ qd, const unsigned long long* __restrict__ dbb,
    unsigned long long* __restrict__ seg_g, unsigned int* __restrict__ cnt_g)
{
  __shared__ __align__(16) short db_lds[2][64 * 256];    // 2 x 32768 B
  __shared__ unsigned seg_lds[4][64][CAPQ][2];           // 40960 B (wave-private)
  __shared__ int lcnt[4][64];                            // 1024 B (wave-private)

  const int tid  = (int)threadIdx.x;
  const int lane = tid & 63;
  const int wv   = tid >> 6;
  const int cid   = (int)blockIdx.x;
  const int mtile = (int)blockIdx.y;
  // chunks 0..53 have 49 subtiles, 54..63 have 48 (covers 3126 subtiles)
  const int nsub = 48 + (cid < 54 ? 1 : 0);
  const int row0 = (48*cid + (cid < 54 ? cid : 54)) << 6;

  lcnt[wv][lane] = 0;   // wave-private, no barrier needed

  const int l15  = lane & 15;
  const int egrp = lane >> 4;
  const int swz  = lane & 7;
  const int rowb = (lane >> 4) << 2;
  const int colb = lane & 15;

  // ---- Q fragments first (their value-waits must not drain the prefetch) ----
  bf16x8 aq[4][8];
  {
    const int kb = egrp << 3;
    #pragma unroll
    for (int fm = 0; fm < 4; ++fm) {
      const int row = mtile*256 + wv*64 + fm*16 + l15;
      #pragma unroll
      for (int kk = 0; kk < 8; ++kk) {
        const float* p = qd + (size_t)row*CDIM + kk*32 + kb;
        float4 x0 = *(const float4*)p;
        float4 x1 = *(const float4*)(p + 4);
        bf16x8 a;
        a[0]=f2bf(x0.x); a[1]=f2bf(x0.y); a[2]=f2bf(x0.z); a[3]=f2bf(x0.w);
        a[4]=f2bf(x1.x); a[5]=f2bf(x1.y); a[6]=f2bf(x1.z); a[7]=f2bf(x1.w);
        aq[fm][kk] = a;
      }
    }
  }

  const char* dbbase = (const char*)dbb;
#define STAGE(bufi, tile) do { \
    const char* _src = dbbase + ((size_t)(row0 + (tile)*64) * 512) + wv*8192 + lane*16; \
    char* _dst = (char*)db_lds[(bufi)] + wv*8192; \
    _Pragma("unroll") \
    for (int _j = 0; _j < 8; ++_j) async_copy16(_src + _j*1024, _dst + _j*1024); \
  } while (0)

  STAGE(0, 0);   // prologue: 8 loads outstanding

  for (int s = 0; s < nsub; ++s) {
    // issue next tile into the other buffer, then wait ONLY for tile s
    if (s + 1 < nsub) {
      STAGE((s + 1) & 1, s + 1);
      asm volatile("s_waitcnt vmcnt(8)" ::: "memory");   // tile s resident (8 newest = s+1)
    } else {
      asm volatile("s_waitcnt vmcnt(0)" ::: "memory");   // last tile: full drain
    }
    __builtin_amdgcn_sched_barrier(0);
    __builtin_amdgcn_s_barrier();                        // all waves: tile s resident
    __builtin_amdgcn_sched_barrier(0);

    // ---- MFMA: 64q x 64db, K=256, swizzled b-frag reads ----
    f32x4 acc[4][4];
    #pragma unroll
    for (int fm = 0; fm < 4; ++fm)
      #pragma unroll
      for (int fn = 0; fn < 4; ++fn)
        acc[fm][fn] = (f32x4){0.f, 0.f, 0.f, 0.f};
    {
      const char* dbt = (const char*)db_lds[s & 1];
      #pragma unroll
      for (int kk = 0; kk < 8; ++kk) {
        const int e = (kk*4 + egrp) ^ swz;
        bf16x8 b[4];
        #pragma unroll
        for (int fn = 0; fn < 4; ++fn)
          b[fn] = *(const bf16x8*)(dbt + (fn*16 + l15)*512 + e*16);
        #pragma unroll
        for (int fn = 0; fn < 4; ++fn) {
          #pragma unroll
          for (int fm = 0; fm < 4; ++fm)
            acc[fm][fn] = __builtin_amdgcn_mfma_f32_16x16x32_bf16(aq[fm][kk], b[fn], acc[fm][fn], 0, 0, 0);
        }
      }
    }

    asm volatile("s_waitcnt lgkmcnt(0)" ::: "memory");   // own ds_reads done
    __builtin_amdgcn_sched_barrier(0);
    __builtin_amdgcn_s_barrier();                        // all waves done reading buf
    __builtin_amdgcn_sched_barrier(0);

    // ---- theta-filter on fragments; LDS-atomic append (overlaps next stage) ----
    {
      const int idxbase = row0 + s*64;
      #pragma unroll
      for (int fm = 0; fm < 4; ++fm)
        #pragma unroll
        for (int fn = 0; fn < 4; ++fn) {
          const f32x4 a = acc[fm][fn];
          const float m = fmaxf(fmaxf(a[0], a[1]), fmaxf(a[2], a[3]));
          if (m > THETA) {                     // taken ~27% of groups wave-wide
            #pragma unroll
            for (int j = 0; j < 4; ++j) {
              if (a[j] > THETA) {
                const int ql = fm*16 + rowb + j;
                const int slot = atomicAdd(&lcnt[wv][ql], 1);
                if (slot < CAPQ) {
                  seg_lds[wv][ql][slot][0] = __float_as_uint(a[j]);
                  seg_lds[wv][ql][slot][1] = (unsigned)(idxbase + fn*16 + colb);
                }
              }
            }
          }
        }
    }
  }
#undef STAGE

  // ---- flush wave-private survivor lists to global ----
  asm volatile("s_waitcnt lgkmcnt(0)" ::: "memory");
  {
    const int cnt = lcnt[wv][lane];
    const int qg = mtile*256 + wv*64 + lane;
    cnt_g[qg*NCH + cid] = (unsigned)cnt;
    const int nc = min(cnt, CAPQ);
    unsigned long long* dst = seg_g + (size_t)(qg*NCH + cid)*CAPQ;
    for (int j = 0; j < nc; ++j) {
      unsigned long long lo = seg_lds[wv][lane][j][0];
      unsigned long long hi = seg_lds[wv][lane][j][1];
      dst[j] = lo | (hi << 32);
    }
  }
}

// ---------------------------------------------------------------------------
// Kernel 2: per-query gather of survivors -> exact top-16 -> vote.
// Self-check: overflow or <16 survivors -> set flag (triggers fallback).
// ---------------------------------------------------------------------------
__global__ __launch_bounds__(64) void gather_vote_kernel(
    const float* __restrict__ pdb,
    const unsigned long long* __restrict__ seg_g, const unsigned* __restrict__ cnt_g,
    int* __restrict__ out_label, float* __restrict__ out_s, int* __restrict__ flag)
{
  __shared__ float    cv[NCH*CAPQ];
  __shared__ unsigned ci[NCH*CAPQ];
  const int q    = (int)blockIdx.x;
  const int lane = (int)threadIdx.x;   // lane == chunk id (64)

  const int cnt = (int)cnt_g[q*NCH + lane];
  const bool over = cnt > CAPQ;
  const int nc = min(cnt, CAPQ);
  int tot = nc;
  #pragma unroll
  for (int off = 32; off >= 1; off >>= 1) tot += __shfl_xor(tot, off);

  const unsigned long long* src = seg_g + (size_t)(q*NCH + lane)*CAPQ;
  for (int j = 0; j < CAPQ; ++j) {
    float v = NEGF; unsigned idx = 0u;
    if (j < nc) {
      const unsigned long long e = src[j];
      v = __uint_as_float((unsigned)e);
      idx = (unsigned)(e >> 32);
    }
    cv[lane*CAPQ + j] = v;
    ci[lane*CAPQ + j] = idx;
  }
  __syncthreads();

  float topv[TK]; int topid[TK];
  #pragma unroll
  for (int r = 0; r < TK; ++r) {
    float bv = NEGF; int bp = -1;
    #pragma unroll 4
    for (int j = 0; j < CAPQ; ++j) {
      const float v = cv[lane*CAPQ + j];
      const int p = lane*CAPQ + j;
      if (v > bv) { bv = v; bp = p; }
    }
    #pragma unroll
    for (int off = 32; off >= 1; off >>= 1) {
      const float ov = __shfl_xor(bv, off);
      const int   op = __shfl_xor(bp, off);
      if (ov > bv || (ov == bv && ((unsigned)op < (unsigned)bp))) { bv = ov; bp = op; }
    }
    topv[r] = bv;
    int id = -2;
    if (bp >= 0 && bv > NEGF) id = (int)pdb[(size_t)ci[bp]*PDBW + CDIM];
    topid[r] = id;
    if (lane == 0 && bp >= 0) cv[bp] = NEGF;
    __syncthreads();
  }

  if (lane == 0) {
    bool mk[TK];
    int nvalid = 0;
    #pragma unroll
    for (int i = 0; i < TK; ++i) {
      mk[i] = (topv[i] >= MIN_SIM_C) && (topid[i] >= 0);
      nvalid += mk[i] ? 1 : 0;
    }
    int maj = 0, majid = 0x7fffffff;
    for (int i = 0; i < TK; ++i) {
      if (!mk[i]) continue;
      int c = 0;
      for (int j = 0; j < TK; ++j) c += (mk[j] && topid[j] == topid[i]) ? 1 : 0;
      if (c > maj || (c == maj && topid[i] < majid)) { maj = c; majid = topid[i]; }
    }
    const float ratio = (float)maj / fmaxf((float)nvalid, 1.0f);
    const bool valid = (maj > 0) && (ratio >= MIN_VOTES_C);
    const int label = valid ? majid : -1;
    float s = 0.f;
    #pragma unroll
    for (int i = 0; i < TK; ++i)
      if (mk[i] && topid[i] == label) s = fmaxf(s, topv[i]);
    out_label[q] = label;
    out_s[q]     = s;
  }
  const bool bad = (__ballot(over) != 0ull) || (tot < TK);
  if (lane == 0 && bad) atomicOr(flag, 1);
}

// ---------------------------------------------------------------------------
// Fallback stage 1 (round-1, proven): gated on flag
// ---------------------------------------------------------------------------
__global__ __launch_bounds__(256, 2) void sims_topk1_kernel(
    const float* __restrict__ qd, const float* __restrict__ pdb,
    float* __restrict__ cand_val, unsigned int* __restrict__ cand_idx,
    const int* __restrict__ gate)
{
  if (gate && *gate == 0) return;
  __shared__ __align__(16) short db_lds[128 * 264];
  float* sims = (float*)db_lds;

  const int tid  = (int)threadIdx.x;
  const int lane = tid & 63;
  const int wv   = tid >> 6;
  const int cid   = (int)blockIdx.x;
  const int mtile = (int)blockIdx.y;

  bf16x8 aq[2][8];
  {
    const int l15 = lane & 15;
    const int kb  = (lane >> 4) << 3;
    #pragma unroll
    for (int fm = 0; fm < 2; ++fm) {
      const int row = mtile*128 + wv*32 + fm*16 + l15;
      #pragma unroll
      for (int kk = 0; kk < 8; ++kk) {
        const float* p = qd + (size_t)row*CDIM + kk*32 + kb;
        float4 x0 = *(const float4*)p;
        float4 x1 = *(const float4*)(p + 4);
        bf16x8 a;
        a[0]=f2bf(x0.x); a[1]=f2bf(x0.y); a[2]=f2bf(x0.z); a[3]=f2bf(x0.w);
        a[4]=f2bf(x1.x); a[5]=f2bf(x1.y); a[6]=f2bf(x1.z); a[7]=f2bf(x1.w);
        aq[fm][kk] = a;
      }
    }
  }

  float    tv[TK];
  unsigned ti[TK];
  #pragma unroll
  for (int i = 0; i < TK; ++i) { tv[i] = NEGF; ti[i] = 0u; }
  float minv = NEGF; int minp = 0;

  const int g0chunk = cid * 4096;
  const int q_l  = tid & 127;
  const int half = tid >> 7;

  for (int s = 0; s < 32; ++s) {
    const int g0 = g0chunk + s*128;
    {
      const int rb = tid >> 6;
      const int c4 = (tid & 63) << 2;
      for (int i = 0; i < 32; ++i) {
        const int rl = i*4 + rb;
        const int g  = g0 + rl;
        float v0, v1, v2, v3;
        if (g < NDB) {
          const float* p = pdb + (size_t)g*PDBW + c4;
          v0 = p[0]; v1 = p[1]; v2 = p[2]; v3 = p[3];
        } else { v0 = v1 = v2 = v3 = 0.f; }
        short* d = &db_lds[rl*264 + c4];
        d[0]=f2bf(v0); d[1]=f2bf(v1); d[2]=f2bf(v2); d[3]=f2bf(v3);
      }
    }
    __syncthreads();

    f32x4 acc[2][8];
    #pragma unroll
    for (int fm = 0; fm < 2; ++fm)
      #pragma unroll
      for (int fn = 0; fn < 8; ++fn)
        acc[fm][fn] = (f32x4){0.f, 0.f, 0.f, 0.f};
    {
      const int l15 = lane & 15;
      const int kb  = (lane >> 4) << 3;
      #pragma unroll
      for (int kk = 0; kk < 8; ++kk) {
        bf16x8 b[8];
        #pragma unroll
        for (int fn = 0; fn < 8; ++fn)
          b[fn] = *(const bf16x8*)&db_lds[(fn*16 + l15)*264 + kk*32 + kb];
        #pragma unroll
        for (int fn = 0; fn < 8; ++fn) {
          acc[0][fn] = __builtin_amdgcn_mfma_f32_16x16x32_bf16(aq[0][kk], b[fn], acc[0][fn], 0, 0, 0);
          acc[1][fn] = __builtin_amdgcn_mfma_f32_16x16x32_bf16(aq[1][kk], b[fn], acc[1][fn], 0, 0, 0);
        }
      }
    }
    __syncthreads();

    {
      const int colb = lane & 15;
      const int rowb = (lane >> 4) << 2;
      #pragma unroll
      for (int fm = 0; fm < 2; ++fm)
        #pragma unroll
        for (int fn = 0; fn < 8; ++fn)
          #pragma unroll
          for (int j = 0; j < 4; ++j)
            sims[(wv*32 + fm*16 + rowb + j)*129 + fn*16 + colb] = acc[fm][fn][j];
    }
    __syncthreads();

    {
      const int cb = half * 64;
      #pragma unroll 4
      for (int c = 0; c < 64; ++c) {
        const int colc = cb + c;
        const float v = sims[q_l*129 + colc];
        const int g = g0 + colc;
        if (v > minv && g < NDB) {
          #pragma unroll
          for (int i = 0; i < TK; ++i) if (i == minp) { tv[i] = v; ti[i] = (unsigned)g; }
          minv = tv[0]; minp = 0;
          #pragma unroll
          for (int i = 1; i < TK; ++i) if (tv[i] < minv) { minv = tv[i]; minp = i; }
        }
      }
    }
    __syncthreads();
  }

  {
    const int qg = mtile*128 + q_l;
    float*    pv = cand_val + ((size_t)qg*NCHUNK1 + cid)*32 + half*TK;
    unsigned* pi = cand_idx + ((size_t)qg*NCHUNK1 + cid)*32 + half*TK;
    #pragma unroll
    for (int i = 0; i < TK; ++i) { pv[i] = tv[i]; pi[i] = ti[i]; }
  }
}

// ---------------------------------------------------------------------------
// Fallback stage 2 (round-1, proven): gated on flag
// ---------------------------------------------------------------------------
template<int CPQ>
__global__ __launch_bounds__(64) void merge_vote_kernel(
    const float* __restrict__ pdb,
    const float* __restrict__ cand_val, const unsigned* __restrict__ cand_idx,
    int* __restrict__ out_label, float* __restrict__ out_s,
    const int* __restrict__ gate)
{
  if (gate && *gate == 0) return;
  __shared__ float    cv[CPQ];
  __shared__ unsigned ci[CPQ];
  const int q    = (int)blockIdx.x;
  const int lane = (int)threadIdx.x;

  for (int j = lane; j < CPQ; j += 64) {
    cv[j] = cand_val[(size_t)q*CPQ + j];
    ci[j] = cand_idx[(size_t)q*CPQ + j];
  }
  __syncthreads();

  float topv[TK]; int topid[TK];
  #pragma unroll
  for (int r = 0; r < TK; ++r) {
    float bv = NEGF; int bp = -1;
    for (int j = lane; j < CPQ; j += 64) {
      const float v = cv[j];
      if (v > bv) { bv = v; bp = j; }
    }
    #pragma unroll
    for (int off = 32; off >= 1; off >>= 1) {
      const float ov = __shfl_xor(bv, off);
      const int   op = __shfl_xor(bp, off);
      if (ov > bv || (ov == bv && ((unsigned)op < (unsigned)bp))) { bv = ov; bp = op; }
    }
    topv[r] = bv;
    int id = -2;
    if (bp >= 0 && bv > NEGF) id = (int)pdb[(size_t)ci[bp]*PDBW + CDIM];
    topid[r] = id;
    if (lane == 0 && bp >= 0) cv[bp] = NEGF;
    __syncthreads();
  }

  if (lane == 0) {
    bool mk[TK];
    int nvalid = 0;
    #pragma unroll
    for (int i = 0; i < TK; ++i) {
      mk[i] = (topv[i] >= MIN_SIM_C) && (topid[i] >= 0);
      nvalid += mk[i] ? 1 : 0;
    }
    int maj = 0, majid = 0x7fffffff;
    for (int i = 0; i < TK; ++i) {
      if (!mk[i]) continue;
      int c = 0;
      for (int j = 0; j < TK; ++j) c += (mk[j] && topid[j] == topid[i]) ? 1 : 0;
      if (c > maj || (c == maj && topid[i] < majid)) { maj = c; majid = topid[i]; }
    }
    const float ratio = (float)maj / fmaxf((float)nvalid, 1.0f);
    const bool valid = (maj > 0) && (ratio >= MIN_VOTES_C);
    const int label = valid ? majid : -1;
    float s = 0.f;
    #pragma unroll
    for (int i = 0; i < TK; ++i)
      if (mk[i] && topid[i] == label) s = fmaxf(s, topv[i]);
    out_label[q] = label;
    out_s[q]     = s;
  }
}

// ---------------------------------------------------------------------------
// Stage 3: overlap removal + final outputs
// ---------------------------------------------------------------------------
__device__ __forceinline__ bool finitef(float v) {
  return ((__float_as_uint(v) >> 23) & 0xffu) != 0xffu;
}

__global__ __launch_bounds__(64) void finalize_kernel(
    const float* __restrict__ boxes, const int* __restrict__ labels,
    const float* __restrict__ svals, float* __restrict__ out)
{
  const int x    = (int)blockIdx.x;
  const int lane = (int)threadIdx.x;
  const int lx = labels[x];
  const float bx1 = boxes[x*4+0], by1 = boxes[x*4+1];
  const float bx2 = boxes[x*4+2], by2 = boxes[x*4+3];
  const float ax = (bx2 - bx1) * (by2 - by1);

  bool flag = false;
  if (lx >= 0) {
    for (int y = lane; y < QN; y += 64) {
      if (y == x) continue;
      if (labels[y] != lx) continue;
      const float c1 = boxes[y*4+0], c2 = boxes[y*4+1];
      const float c3 = boxes[y*4+2], c4 = boxes[y*4+3];
      const float ay = (c3 - c1) * (c4 - c2);
      const float xi1 = fmaxf(bx1, c1), yi1 = fmaxf(by1, c2);
      const float xi2 = fminf(bx2, c3), yi2 = fminf(by2, c4);
      const float inter = fmaxf(xi2 - xi1, 0.f) * fmaxf(yi2 - yi1, 0.f);
      const float asmall = fminf(ax, ay);
      const float ov = (asmall > 0.f) ? inter / fmaxf(asmall, 1e-12f) : 0.f;
      if (ov >= 0.5f && ay <= ax) flag = true;
    }
  }
  const bool removed = (__ballot(flag) != 0ull);
  const int label = removed ? -1 : lx;
  const float s = svals[x];
  const bool fin = finitef(s) && finitef(bx1) && finitef(by1) && finitef(bx2) && finitef(by2);
  const bool valid = (label >= 0) && fin;

  if (lane == 0) {
    out[4096 + x] = valid ? s : 0.f;
    out[5120 + x] = (float)(valid ? label : -1);
  }
  if (lane < 4) out[x*4 + lane] = boxes[x*4 + lane];
}

// ---------------------------------------------------------------------------
extern "C" void kernel_launch(void* const* d_in, const int* in_sizes, int n_in,
                              void* d_out, int out_size, void* d_ws, size_t ws_size,
                              hipStream_t stream)
{
  const float* boxes = (const float*)d_in[0];
  const float* qd    = (const float*)d_in[1];
  const float* pdb   = (const float*)d_in[2];
  float* out = (float*)d_out;
  char* ws = (char*)d_ws;

  const size_t db_bytes  = (size_t)NDB_PAD * 512;             // 102,432,768
  const size_t seg_bytes = (size_t)QN * NCH * CAPQ * 8;       // 10,485,760
  const size_t cnt_bytes = (size_t)QN * NCH * 4;              //    262,144
  const size_t c1_bytes  = (size_t)QN * CPQ1 * 8;             // 12,845,056 (fallback, aliases seg+cnt)
  const size_t A_bytes   = (seg_bytes + cnt_bytes > c1_bytes) ? seg_bytes + cnt_bytes : c1_bytes;
  const size_t need = db_bytes + A_bytes + (size_t)QN*8 + 64;

  if (ws_size >= need) {
    unsigned long long* dbb = (unsigned long long*)ws;
    char* A = ws + db_bytes;
    unsigned long long* seg_g = (unsigned long long*)A;
    unsigned*           cnt_g = (unsigned*)(A + seg_bytes);
    float*    cand_val = (float*)A;
    unsigned* cand_idx = (unsigned*)(A + (size_t)QN*CPQ1*4);
    int*      labels   = (int*)(ws + db_bytes + A_bytes);
    float*    svals    = (float*)(ws + db_bytes + A_bytes + (size_t)QN*4);
    int*      flag     = (int*)(ws + db_bytes + A_bytes + (size_t)QN*8);

    hipMemsetAsync(flag, 0, 4, stream);
    hipLaunchKernelGGL(convert_db_kernel, dim3(2048), dim3(256), 0, stream, pdb, dbb);
    hipLaunchKernelGGL(sims_filter_kernel, dim3(NCH, 4), dim3(256), 0, stream,
                       qd, dbb, seg_g, cnt_g);
    hipLaunchKernelGGL(gather_vote_kernel, dim3(QN), dim3(64), 0, stream,
                       pdb, seg_g, cnt_g, labels, svals, flag);
    hipLaunchKernelGGL(sims_topk1_kernel, dim3(NCHUNK1, 8), dim3(256), 0, stream,
                       qd, pdb, cand_val, cand_idx, flag);
    hipLaunchKernelGGL((merge_vote_kernel<CPQ1>), dim3(QN), dim3(64), 0, stream,
                       pdb, cand_val, cand_idx, labels, svals, flag);
    hipLaunchKernelGGL(finalize_kernel, dim3(QN), dim3(64), 0, stream,
                       boxes, labels, svals, out);
  } else {
    const size_t n1 = (size_t)QN * CPQ1;
    float*    cand_val = (float*)ws;
    unsigned* cand_idx = (unsigned*)(ws + n1*4);
    int*      labels   = (int*)(ws + n1*8);
    float*    svals    = (float*)(ws + n1*8 + (size_t)QN*4);

    hipLaunchKernelGGL(sims_topk1_kernel, dim3(NCHUNK1, 8), dim3(256), 0, stream,
                       qd, pdb, cand_val, cand_idx, (const int*)nullptr);
    hipLaunchKernelGGL((merge_vote_kernel<CPQ1>), dim3(QN), dim3(64), 0, stream,
                       pdb, cand_val, cand_idx, labels, svals, (const int*)nullptr);
    hipLaunchKernelGGL(finalize_kernel, dim3(QN), dim3(64), 0, stream,
                       boxes, labels, svals, out);
  }
}

// Round 5
// 211.476 us; speedup vs baseline: 1.2109x; 1.2109x over previous
//
#include <hip/hip_runtime.h>
#include <hip/hip_bf16.h>

// ---------------- problem constants ----------------
#define QN 1024
#define NDB 200000
#define NDB_PAD 200064        // 3126 subtiles of 64 rows
#define PDBW 257
#define CDIM 256
#define TK 16
#define NEGF (-1e30f)
#define MIN_SIM_C 0.05f
#define MIN_VOTES_C 0.3f

// fast path: 128 chunks x 2 query-tiles (512 q/block, 8 waves); fp8 filter
#define NCH 128
#define THETA 0.19f           // P(sim>THETA)=1.18e-3; true 16th-best ~0.236 (fp8 err 3e-3 -> 15 sigma)
#define CAPQ 16               // per-(query,chunk) cap (lambda~1.9, P(over) ~ 2e-11/cell)
// fallback (round-1, proven) path
#define NCHUNK1 49
#define CPQ1 (NCHUNK1*32)

typedef __attribute__((ext_vector_type(8))) short bf16x8;
typedef __attribute__((ext_vector_type(4))) float f32x4;

__device__ __forceinline__ short f2bf(float f) {
  union { float f; unsigned u; } x; x.f = f;
  unsigned u = x.u;
  return (short)((u + 0x7fffu + ((u >> 16) & 1u)) >> 16);  // RNE
}

__device__ __forceinline__ void async_copy16(const void* gp, void* lp) {
  __builtin_amdgcn_global_load_lds(
      (__attribute__((address_space(1))) void*)gp,
      (__attribute__((address_space(3))) void*)lp, 16, 0, 0);
}

// pack 4 floats -> 4 fp8 bytes (native gfx950 format; same converter feeds A and B,
// so any k-slot permutation cancels in the MFMA dot product)
__device__ __forceinline__ unsigned pk_fp8x4(float a, float b, float c, float d) {
  unsigned w = (unsigned)__builtin_amdgcn_cvt_pk_fp8_f32(a, b, 0, false);
  w = (unsigned)__builtin_amdgcn_cvt_pk_fp8_f32(c, d, (int)w, true);
  return w;
}

// ---------------------------------------------------------------------------
// Kernel 0: pdb fp32 -> fp8 e4m3, 8B-piece swizzle (p -> p ^ ((r&15)<<1)),
// zero-pad rows [NDB, NDB_PAD). One wave per row; lane covers 4 elems (4B out).
// ---------------------------------------------------------------------------
__global__ __launch_bounds__(256) void convert_db_kernel(
    const float* __restrict__ pdb, unsigned char* __restrict__ dbb)
{
  const int wv = (int)threadIdx.x >> 6, lane = (int)threadIdx.x & 63;
  for (int r = (int)blockIdx.x*4 + wv; r < NDB_PAD; r += (int)gridDim.x*4) {
    unsigned pack = 0u;
    if (r < NDB) {
      const float* p = pdb + (size_t)r*PDBW + lane*4;
      pack = pk_fp8x4(p[0], p[1], p[2], p[3]);
    }
    const int piece = lane >> 1;                       // 8B piece index 0..31
    const int ps    = piece ^ ((r & 15) << 1);         // bank-spread swizzle
    *(unsigned*)(dbb + (size_t)r*256 + ps*8 + (lane & 1)*4) = pack;
  }
}

// ---------------------------------------------------------------------------
// Kernel 1: fp8 MFMA sims + register theta-filter + LDS survivor append.
// grid (128, 2), 512 thr (8 waves x 64 queries). Subtile = 64 db rows (16KB).
// Double-buffered LDS + counted vmcnt(2) + raw barriers. 98KB LDS ->
// 1 block/CU = 8 waves = 2 waves/SIMD (TLP restored vs round 4).
// ---------------------------------------------------------------------------
__global__ __launch_bounds__(512, 2) void sims_filter_kernel(
    const float* __restrict__ qd, const unsigned char* __restrict__ dbb,
    unsigned long long* __restrict__ seg_g, unsigned int* __restrict__ cnt_g)
{
  __shared__ __align__(16) char db_lds[2][64 * 256];   // 2 x 16384 B (fp8)
  __shared__ unsigned seg_lds[8][64][CAPQ][2];         // 65536 B (wave-private)
  __shared__ int lcnt[8][64];                          // 2048 B (wave-private)

  const int tid  = (int)threadIdx.x;
  const int lane = tid & 63;
  const int wv   = tid >> 6;          // 0..7
  const int cid   = (int)blockIdx.x;  // 0..127
  const int mtile = (int)blockIdx.y;  // 0..1
  // chunks 0..53 have 25 subtiles, 54..127 have 24 (covers 3126 subtiles)
  const int nsub = 24 + (cid < 54 ? 1 : 0);
  const int row0 = (24*cid + (cid < 54 ? cid : 54)) << 6;

  lcnt[wv][lane] = 0;   // wave-private, no barrier needed

  const int l15  = lane & 15;
  const int egrp = lane >> 4;
  const int rowb = egrp << 2;
  const int colb = l15;

  // ---- Q fragments: fp32 -> fp8 packed i64, once per block ----
  long aq[4][8];
  {
    const int kb = egrp << 3;
    #pragma unroll
    for (int fm = 0; fm < 4; ++fm) {
      const int row = mtile*512 + wv*64 + fm*16 + l15;
      #pragma unroll
      for (int kk = 0; kk < 8; ++kk) {
        const float* p = qd + (size_t)row*CDIM + kk*32 + kb;
        float4 x0 = *(const float4*)p;
        float4 x1 = *(const float4*)(p + 4);
        unsigned lo = pk_fp8x4(x0.x, x0.y, x0.z, x0.w);
        unsigned hi = pk_fp8x4(x1.x, x1.y, x1.z, x1.w);
        aq[fm][kk] = (long)(((unsigned long long)hi << 32) | lo);
      }
    }
  }

  const char* dbbase = (const char*)dbb;
#define STAGE(bufi, tile) do { \
    const char* _src = dbbase + ((size_t)(row0 + (tile)*64) * 256) + wv*2048 + lane*16; \
    char* _dst = (char*)db_lds[(bufi)] + wv*2048; \
    async_copy16(_src,        _dst); \
    async_copy16(_src + 1024, _dst + 1024); \
  } while (0)

  STAGE(0, 0);   // prologue: 2 loads outstanding per thread

  for (int s = 0; s < nsub; ++s) {
    // issue next tile into the other buffer, then wait ONLY for tile s
    if (s + 1 < nsub) {
      STAGE((s + 1) & 1, s + 1);
      asm volatile("s_waitcnt vmcnt(2)" ::: "memory");   // tile s resident (2 newest = s+1)
    } else {
      asm volatile("s_waitcnt vmcnt(0)" ::: "memory");   // last tile: full drain
    }
    __builtin_amdgcn_sched_barrier(0);
    __builtin_amdgcn_s_barrier();                        // all waves: tile s resident
    __builtin_amdgcn_sched_barrier(0);

    // ---- MFMA: 64q x 64db, K=256, fp8, swizzled b64 reads (<=2-way) ----
    f32x4 acc[4][4];
    #pragma unroll
    for (int fm = 0; fm < 4; ++fm)
      #pragma unroll
      for (int fn = 0; fn < 4; ++fn)
        acc[fm][fn] = (f32x4){0.f, 0.f, 0.f, 0.f};
    {
      const char* dbt = (const char*)db_lds[s & 1];
      #pragma unroll
      for (int kk = 0; kk < 8; ++kk) {
        const int ps = ((kk*4 + egrp) ^ (l15 << 1)) << 3;
        long b[4];
        #pragma unroll
        for (int fn = 0; fn < 4; ++fn)
          b[fn] = *(const long*)(dbt + (fn*16 + l15)*256 + ps);
        #pragma unroll
        for (int fn = 0; fn < 4; ++fn) {
          #pragma unroll
          for (int fm = 0; fm < 4; ++fm)
            acc[fm][fn] = __builtin_amdgcn_mfma_f32_16x16x32_fp8_fp8(aq[fm][kk], b[fn], acc[fm][fn], 0, 0, 0);
        }
      }
    }

    asm volatile("s_waitcnt lgkmcnt(0)" ::: "memory");   // own ds_reads done
    __builtin_amdgcn_sched_barrier(0);
    __builtin_amdgcn_s_barrier();                        // all waves done reading buf
    __builtin_amdgcn_sched_barrier(0);

    // ---- theta-filter on fragments; LDS-atomic append ----
    {
      const int idxbase = row0 + s*64;
      #pragma unroll
      for (int fm = 0; fm < 4; ++fm)
        #pragma unroll
        for (int fn = 0; fn < 4; ++fn) {
          const f32x4 a = acc[fm][fn];
          const float m = fmaxf(fmaxf(a[0], a[1]), fmaxf(a[2], a[3]));
          if (m > THETA) {
            #pragma unroll
            for (int j = 0; j < 4; ++j) {
              if (a[j] > THETA) {
                const int ql = fm*16 + rowb + j;
                const int slot = atomicAdd(&lcnt[wv][ql], 1);
                if (slot < CAPQ) {
                  seg_lds[wv][ql][slot][0] = __float_as_uint(a[j]);
                  seg_lds[wv][ql][slot][1] = (unsigned)(idxbase + fn*16 + colb);
                }
              }
            }
          }
        }
    }
  }
#undef STAGE

  // ---- flush wave-private survivor lists to global ----
  asm volatile("s_waitcnt lgkmcnt(0)" ::: "memory");
  {
    const int cnt = lcnt[wv][lane];
    const int qg = mtile*512 + wv*64 + lane;
    cnt_g[qg*NCH + cid] = (unsigned)cnt;
    const int nc = min(cnt, CAPQ);
    unsigned long long* dst = seg_g + (size_t)(qg*NCH + cid)*CAPQ;
    for (int j = 0; j < nc; ++j) {
      unsigned long long lo = seg_lds[wv][lane][j][0];
      unsigned long long hi = seg_lds[wv][lane][j][1];
      dst[j] = lo | (hi << 32);
    }
  }
}

// ---------------------------------------------------------------------------
// Kernel 2: per-query gather of survivors -> exact top-16 -> vote.
// Self-check: overflow or <16 survivors -> set flag (triggers fallback).
// ---------------------------------------------------------------------------
__global__ __launch_bounds__(64) void gather_vote_kernel(
    const float* __restrict__ pdb,
    const unsigned long long* __restrict__ seg_g, const unsigned* __restrict__ cnt_g,
    int* __restrict__ out_label, float* __restrict__ out_s, int* __restrict__ flag)
{
  __shared__ float    cv[NCH*CAPQ];   // 2048
  __shared__ unsigned ci[NCH*CAPQ];
  const int q    = (int)blockIdx.x;
  const int lane = (int)threadIdx.x;

  bool over = false;
  int tot = 0;
  #pragma unroll
  for (int h = 0; h < 2; ++h) {
    const int c = h*64 + lane;
    const int cnt = (int)cnt_g[q*NCH + c];
    over |= (cnt > CAPQ);
    const int nc = min(cnt, CAPQ);
    tot += nc;
    const unsigned long long* src = seg_g + (size_t)(q*NCH + c)*CAPQ;
    for (int j = 0; j < CAPQ; ++j) {
      float v = NEGF; unsigned idx = 0u;
      if (j < nc) {
        const unsigned long long e = src[j];
        v = __uint_as_float((unsigned)e);
        idx = (unsigned)(e >> 32);
      }
      cv[c*CAPQ + j] = v;
      ci[c*CAPQ + j] = idx;
    }
  }
  #pragma unroll
  for (int off = 32; off >= 1; off >>= 1) tot += __shfl_xor(tot, off);
  __syncthreads();

  float topv[TK]; int topid[TK];
  #pragma unroll
  for (int r = 0; r < TK; ++r) {
    float bv = NEGF; int bp = -1;
    #pragma unroll 4
    for (int j = 0; j < 32; ++j) {
      const int p = j*64 + lane;
      const float v = cv[p];
      if (v > bv) { bv = v; bp = p; }
    }
    #pragma unroll
    for (int off = 32; off >= 1; off >>= 1) {
      const float ov = __shfl_xor(bv, off);
      const int   op = __shfl_xor(bp, off);
      if (ov > bv || (ov == bv && ((unsigned)op < (unsigned)bp))) { bv = ov; bp = op; }
    }
    topv[r] = bv;
    int id = -2;
    if (bp >= 0 && bv > NEGF) id = (int)pdb[(size_t)ci[bp]*PDBW + CDIM];
    topid[r] = id;
    if (lane == 0 && bp >= 0) cv[bp] = NEGF;
    __syncthreads();
  }

  if (lane == 0) {
    bool mk[TK];
    int nvalid = 0;
    #pragma unroll
    for (int i = 0; i < TK; ++i) {
      mk[i] = (topv[i] >= MIN_SIM_C) && (topid[i] >= 0);
      nvalid += mk[i] ? 1 : 0;
    }
    int maj = 0, majid = 0x7fffffff;
    for (int i = 0; i < TK; ++i) {
      if (!mk[i]) continue;
      int c = 0;
      for (int j = 0; j < TK; ++j) c += (mk[j] && topid[j] == topid[i]) ? 1 : 0;
      if (c > maj || (c == maj && topid[i] < majid)) { maj = c; majid = topid[i]; }
    }
    const float ratio = (float)maj / fmaxf((float)nvalid, 1.0f);
    const bool valid = (maj > 0) && (ratio >= MIN_VOTES_C);
    const int label = valid ? majid : -1;
    float s = 0.f;
    #pragma unroll
    for (int i = 0; i < TK; ++i)
      if (mk[i] && topid[i] == label) s = fmaxf(s, topv[i]);
    out_label[q] = label;
    out_s[q]     = s;
  }
  const bool bad = (__ballot(over) != 0ull) || (tot < TK);
  if (lane == 0 && bad) atomicOr(flag, 1);
}

// ---------------------------------------------------------------------------
// Fallback stage 1 (round-1, proven): gated on flag
// ---------------------------------------------------------------------------
__global__ __launch_bounds__(256, 2) void sims_topk1_kernel(
    const float* __restrict__ qd, const float* __restrict__ pdb,
    float* __restrict__ cand_val, unsigned int* __restrict__ cand_idx,
    const int* __restrict__ gate)
{
  if (gate && *gate == 0) return;
  __shared__ __align__(16) short db_lds[128 * 264];
  float* sims = (float*)db_lds;

  const int tid  = (int)threadIdx.x;
  const int lane = tid & 63;
  const int wv   = tid >> 6;
  const int cid   = (int)blockIdx.x;
  const int mtile = (int)blockIdx.y;

  bf16x8 aq[2][8];
  {
    const int l15 = lane & 15;
    const int kb  = (lane >> 4) << 3;
    #pragma unroll
    for (int fm = 0; fm < 2; ++fm) {
      const int row = mtile*128 + wv*32 + fm*16 + l15;
      #pragma unroll
      for (int kk = 0; kk < 8; ++kk) {
        const float* p = qd + (size_t)row*CDIM + kk*32 + kb;
        float4 x0 = *(const float4*)p;
        float4 x1 = *(const float4*)(p + 4);
        bf16x8 a;
        a[0]=f2bf(x0.x); a[1]=f2bf(x0.y); a[2]=f2bf(x0.z); a[3]=f2bf(x0.w);
        a[4]=f2bf(x1.x); a[5]=f2bf(x1.y); a[6]=f2bf(x1.z); a[7]=f2bf(x1.w);
        aq[fm][kk] = a;
      }
    }
  }

  float    tv[TK];
  unsigned ti[TK];
  #pragma unroll
  for (int i = 0; i < TK; ++i) { tv[i] = NEGF; ti[i] = 0u; }
  float minv = NEGF; int minp = 0;

  const int g0chunk = cid * 4096;
  const int q_l  = tid & 127;
  const int half = tid >> 7;

  for (int s = 0; s < 32; ++s) {
    const int g0 = g0chunk + s*128;
    {
      const int rb = tid >> 6;
      const int c4 = (tid & 63) << 2;
      for (int i = 0; i < 32; ++i) {
        const int rl = i*4 + rb;
        const int g  = g0 + rl;
        float v0, v1, v2, v3;
        if (g < NDB) {
          const float* p = pdb + (size_t)g*PDBW + c4;
          v0 = p[0]; v1 = p[1]; v2 = p[2]; v3 = p[3];
        } else { v0 = v1 = v2 = v3 = 0.f; }
        short* d = &db_lds[rl*264 + c4];
        d[0]=f2bf(v0); d[1]=f2bf(v1); d[2]=f2bf(v2); d[3]=f2bf(v3);
      }
    }
    __syncthreads();

    f32x4 acc[2][8];
    #pragma unroll
    for (int fm = 0; fm < 2; ++fm)
      #pragma unroll
      for (int fn = 0; fn < 8; ++fn)
        acc[fm][fn] = (f32x4){0.f, 0.f, 0.f, 0.f};
    {
      const int l15 = lane & 15;
      const int kb  = (lane >> 4) << 3;
      #pragma unroll
      for (int kk = 0; kk < 8; ++kk) {
        bf16x8 b[8];
        #pragma unroll
        for (int fn = 0; fn < 8; ++fn)
          b[fn] = *(const bf16x8*)&db_lds[(fn*16 + l15)*264 + kk*32 + kb];
        #pragma unroll
        for (int fn = 0; fn < 8; ++fn) {
          acc[0][fn] = __builtin_amdgcn_mfma_f32_16x16x32_bf16(aq[0][kk], b[fn], acc[0][fn], 0, 0, 0);
          acc[1][fn] = __builtin_amdgcn_mfma_f32_16x16x32_bf16(aq[1][kk], b[fn], acc[1][fn], 0, 0, 0);
        }
      }
    }
    __syncthreads();

    {
      const int colb = lane & 15;
      const int rowb = (lane >> 4) << 2;
      #pragma unroll
      for (int fm = 0; fm < 2; ++fm)
        #pragma unroll
        for (int fn = 0; fn < 8; ++fn)
          #pragma unroll
          for (int j = 0; j < 4; ++j)
            sims[(wv*32 + fm*16 + rowb + j)*129 + fn*16 + colb] = acc[fm][fn][j];
    }
    __syncthreads();

    {
      const int cb = half * 64;
      #pragma unroll 4
      for (int c = 0; c < 64; ++c) {
        const int colc = cb + c;
        const float v = sims[q_l*129 + colc];
        const int g = g0 + colc;
        if (v > minv && g < NDB) {
          #pragma unroll
          for (int i = 0; i < TK; ++i) if (i == minp) { tv[i] = v; ti[i] = (unsigned)g; }
          minv = tv[0]; minp = 0;
          #pragma unroll
          for (int i = 1; i < TK; ++i) if (tv[i] < minv) { minv = tv[i]; minp = i; }
        }
      }
    }
    __syncthreads();
  }

  {
    const int qg = mtile*128 + q_l;
    float*    pv = cand_val + ((size_t)qg*NCHUNK1 + cid)*32 + half*TK;
    unsigned* pi = cand_idx + ((size_t)qg*NCHUNK1 + cid)*32 + half*TK;
    #pragma unroll
    for (int i = 0; i < TK; ++i) { pv[i] = tv[i]; pi[i] = ti[i]; }
  }
}

// ---------------------------------------------------------------------------
// Fallback stage 2 (round-1, proven): gated on flag
// ---------------------------------------------------------------------------
template<int CPQ>
__global__ __launch_bounds__(64) void merge_vote_kernel(
    const float* __restrict__ pdb,
    const float* __restrict__ cand_val, const unsigned* __restrict__ cand_idx,
    int* __restrict__ out_label, float* __restrict__ out_s,
    const int* __restrict__ gate)
{
  if (gate && *gate == 0) return;
  __shared__ float    cv[CPQ];
  __shared__ unsigned ci[CPQ];
  const int q    = (int)blockIdx.x;
  const int lane = (int)threadIdx.x;

  for (int j = lane; j < CPQ; j += 64) {
    cv[j] = cand_val[(size_t)q*CPQ + j];
    ci[j] = cand_idx[(size_t)q*CPQ + j];
  }
  __syncthreads();

  float topv[TK]; int topid[TK];
  #pragma unroll
  for (int r = 0; r < TK; ++r) {
    float bv = NEGF; int bp = -1;
    for (int j = lane; j < CPQ; j += 64) {
      const float v = cv[j];
      if (v > bv) { bv = v; bp = j; }
    }
    #pragma unroll
    for (int off = 32; off >= 1; off >>= 1) {
      const float ov = __shfl_xor(bv, off);
      const int   op = __shfl_xor(bp, off);
      if (ov > bv || (ov == bv && ((unsigned)op < (unsigned)bp))) { bv = ov; bp = op; }
    }
    topv[r] = bv;
    int id = -2;
    if (bp >= 0 && bv > NEGF) id = (int)pdb[(size_t)ci[bp]*PDBW + CDIM];
    topid[r] = id;
    if (lane == 0 && bp >= 0) cv[bp] = NEGF;
    __syncthreads();
  }

  if (lane == 0) {
    bool mk[TK];
    int nvalid = 0;
    #pragma unroll
    for (int i = 0; i < TK; ++i) {
      mk[i] = (topv[i] >= MIN_SIM_C) && (topid[i] >= 0);
      nvalid += mk[i] ? 1 : 0;
    }
    int maj = 0, majid = 0x7fffffff;
    for (int i = 0; i < TK; ++i) {
      if (!mk[i]) continue;
      int c = 0;
      for (int j = 0; j < TK; ++j) c += (mk[j] && topid[j] == topid[i]) ? 1 : 0;
      if (c > maj || (c == maj && topid[i] < majid)) { maj = c; majid = topid[i]; }
    }
    const float ratio = (float)maj / fmaxf((float)nvalid, 1.0f);
    const bool valid = (maj > 0) && (ratio >= MIN_VOTES_C);
    const int label = valid ? majid : -1;
    float s = 0.f;
    #pragma unroll
    for (int i = 0; i < TK; ++i)
      if (mk[i] && topid[i] == label) s = fmaxf(s, topv[i]);
    out_label[q] = label;
    out_s[q]     = s;
  }
}

// ---------------------------------------------------------------------------
// Stage 3: overlap removal + final outputs
// ---------------------------------------------------------------------------
__device__ __forceinline__ bool finitef(float v) {
  return ((__float_as_uint(v) >> 23) & 0xffu) != 0xffu;
}

__global__ __launch_bounds__(64) void finalize_kernel(
    const float* __restrict__ boxes, const int* __restrict__ labels,
    const float* __restrict__ svals, float* __restrict__ out)
{
  const int x    = (int)blockIdx.x;
  const int lane = (int)threadIdx.x;
  const int lx = labels[x];
  const float bx1 = boxes[x*4+0], by1 = boxes[x*4+1];
  const float bx2 = boxes[x*4+2], by2 = boxes[x*4+3];
  const float ax = (bx2 - bx1) * (by2 - by1);

  bool flag = false;
  if (lx >= 0) {
    for (int y = lane; y < QN; y += 64) {
      if (y == x) continue;
      if (labels[y] != lx) continue;
      const float c1 = boxes[y*4+0], c2 = boxes[y*4+1];
      const float c3 = boxes[y*4+2], c4 = boxes[y*4+3];
      const float ay = (c3 - c1) * (c4 - c2);
      const float xi1 = fmaxf(bx1, c1), yi1 = fmaxf(by1, c2);
      const float xi2 = fminf(bx2, c3), yi2 = fminf(by2, c4);
      const float inter = fmaxf(xi2 - xi1, 0.f) * fmaxf(yi2 - yi1, 0.f);
      const float asmall = fminf(ax, ay);
      const float ov = (asmall > 0.f) ? inter / fmaxf(asmall, 1e-12f) : 0.f;
      if (ov >= 0.5f && ay <= ax) flag = true;
    }
  }
  const bool removed = (__ballot(flag) != 0ull);
  const int label = removed ? -1 : lx;
  const float s = svals[x];
  const bool fin = finitef(s) && finitef(bx1) && finitef(by1) && finitef(bx2) && finitef(by2);
  const bool valid = (label >= 0) && fin;

  if (lane == 0) {
    out[4096 + x] = valid ? s : 0.f;
    out[5120 + x] = (float)(valid ? label : -1);
  }
  if (lane < 4) out[x*4 + lane] = boxes[x*4 + lane];
}

// ---------------------------------------------------------------------------
extern "C" void kernel_launch(void* const* d_in, const int* in_sizes, int n_in,
                              void* d_out, int out_size, void* d_ws, size_t ws_size,
                              hipStream_t stream)
{
  const float* boxes = (const float*)d_in[0];
  const float* qd    = (const float*)d_in[1];
  const float* pdb   = (const float*)d_in[2];
  float* out = (float*)d_out;
  char* ws = (char*)d_ws;

  const size_t db_bytes  = (size_t)NDB_PAD * 256;             //  51,216,384 (fp8)
  const size_t seg_bytes = (size_t)QN * NCH * CAPQ * 8;       //  16,777,216
  const size_t cnt_bytes = (size_t)QN * NCH * 4;              //     524,288
  const size_t c1_bytes  = (size_t)QN * CPQ1 * 8;             //  12,845,056 (fallback, aliases seg+cnt)
  const size_t A_bytes   = (seg_bytes + cnt_bytes > c1_bytes) ? seg_bytes + cnt_bytes : c1_bytes;
  const size_t need = db_bytes + A_bytes + (size_t)QN*8 + 64;

  if (ws_size >= need) {
    unsigned char* dbb = (unsigned char*)ws;
    char* A = ws + db_bytes;
    unsigned long long* seg_g = (unsigned long long*)A;
    unsigned*           cnt_g = (unsigned*)(A + seg_bytes);
    float*    cand_val = (float*)A;
    unsigned* cand_idx = (unsigned*)(A + (size_t)QN*CPQ1*4);
    int*      labels   = (int*)(ws + db_bytes + A_bytes);
    float*    svals    = (float*)(ws + db_bytes + A_bytes + (size_t)QN*4);
    int*      flag     = (int*)(ws + db_bytes + A_bytes + (size_t)QN*8);

    hipMemsetAsync(flag, 0, 4, stream);
    hipLaunchKernelGGL(convert_db_kernel, dim3(2048), dim3(256), 0, stream, pdb, dbb);
    hipLaunchKernelGGL(sims_filter_kernel, dim3(NCH, 2), dim3(512), 0, stream,
                       qd, dbb, seg_g, cnt_g);
    hipLaunchKernelGGL(gather_vote_kernel, dim3(QN), dim3(64), 0, stream,
                       pdb, seg_g, cnt_g, labels, svals, flag);
    hipLaunchKernelGGL(sims_topk1_kernel, dim3(NCHUNK1, 8), dim3(256), 0, stream,
                       qd, pdb, cand_val, cand_idx, flag);
    hipLaunchKernelGGL((merge_vote_kernel<CPQ1>), dim3(QN), dim3(64), 0, stream,
                       pdb, cand_val, cand_idx, labels, svals, flag);
    hipLaunchKernelGGL(finalize_kernel, dim3(QN), dim3(64), 0, stream,
                       boxes, labels, svals, out);
  } else {
    const size_t n1 = (size_t)QN * CPQ1;
    float*    cand_val = (float*)ws;
    unsigned* cand_idx = (unsigned*)(ws + n1*4);
    int*      labels   = (int*)(ws + n1*8);
    float*    svals    = (float*)(ws + n1*8 + (size_t)QN*4);

    hipLaunchKernelGGL(sims_topk1_kernel, dim3(NCHUNK1, 8), dim3(256), 0, stream,
                       qd, pdb, cand_val, cand_idx, (const int*)nullptr);
    hipLaunchKernelGGL((merge_vote_kernel<CPQ1>), dim3(QN), dim3(64), 0, stream,
                       pdb, cand_val, cand_idx, labels, svals, (const int*)nullptr);
    hipLaunchKernelGGL(finalize_kernel, dim3(QN), dim3(64), 0, stream,
                       boxes, labels, svals, out);
  }
}

// Round 6
// 178.196 us; speedup vs baseline: 1.4371x; 1.1868x over previous
//
#include <hip/hip_runtime.h>
#include <hip/hip_bf16.h>

// ---------------- problem constants ----------------
#define QN 1024
#define NDB 200000
#define NDB_PAD 200064        // 3126 subtiles of 64 rows
#define PDBW 257
#define CDIM 256
#define TK 16
#define NEGF (-1e30f)
#define MIN_SIM_C 0.05f
#define MIN_VOTES_C 0.3f

// fast path: 128 chunks x 4 query-tiles (256 q/block, 4 waves); MX-fp8 filter
#define NCH 128
#define THETA 0.19f           // P(sim>THETA)=1.18e-3; true 16th-best ~0.236 (fp8 err ~3e-3 -> ~15 sigma)
#define CAPQ 14               // per-(query,chunk) cap (lambda~1.84, P(over)~1e-9/cell)
// fallback (round-1, proven) path
#define NCHUNK1 49
#define CPQ1 (NCHUNK1*32)

typedef __attribute__((ext_vector_type(8))) short bf16x8;
typedef __attribute__((ext_vector_type(4))) float f32x4;
typedef __attribute__((ext_vector_type(8))) int   i32x8;
typedef __attribute__((ext_vector_type(4))) int   i32x4;

__device__ __forceinline__ short f2bf(float f) {
  union { float f; unsigned u; } x; x.f = f;
  unsigned u = x.u;
  return (short)((u + 0x7fffu + ((u >> 16) & 1u)) >> 16);  // RNE
}

__device__ __forceinline__ void async_copy16(const void* gp, void* lp) {
  __builtin_amdgcn_global_load_lds(
      (__attribute__((address_space(1))) void*)gp,
      (__attribute__((address_space(3))) void*)lp, 16, 0, 0);
}

// pack 4 floats -> 4 fp8 e4m3 bytes (same converter feeds A and B, so any
// consistent lane-position->k mapping cancels in the MFMA dot product)
__device__ __forceinline__ unsigned pk_fp8x4(float a, float b, float c, float d) {
  unsigned w = (unsigned)__builtin_amdgcn_cvt_pk_fp8_f32(a, b, 0, false);
  w = (unsigned)__builtin_amdgcn_cvt_pk_fp8_f32(c, d, (int)w, true);
  return w;
}

// ---------------------------------------------------------------------------
// Kernel 0: pdb fp32 -> fp8 e4m3, 16B-pair swizzle (pair m -> m ^ (r&15)),
// zero-pad rows [NDB, NDB_PAD). One wave per row; lane covers 4 elems.
// ---------------------------------------------------------------------------
__global__ __launch_bounds__(256) void convert_db_kernel(
    const float* __restrict__ pdb, unsigned char* __restrict__ dbb)
{
  const int wv = (int)threadIdx.x >> 6, lane = (int)threadIdx.x & 63;
  for (int r = (int)blockIdx.x*4 + wv; r < NDB_PAD; r += (int)gridDim.x*4) {
    unsigned pack = 0u;
    if (r < NDB) {
      const float* p = pdb + (size_t)r*PDBW + lane*4;
      pack = pk_fp8x4(p[0], p[1], p[2], p[3]);
    }
    const int piece = lane >> 1;                       // 8B piece index 0..31
    const int ps    = piece ^ ((r & 15) << 1);         // == 16B-pair ^ (r&15)
    *(unsigned*)(dbb + (size_t)r*256 + ps*8 + (lane & 1)*4) = pack;
  }
}

// ---------------------------------------------------------------------------
// Kernel 1: MX-fp8 (K=128, unit scale) MFMA sims + register theta-filter +
// direct-global survivor stores (slot via tiny LDS-atomic counter).
// grid (128, 4), 256 thr (4 waves x 64 queries). Subtile = 64 db rows (16KB).
// Double-buffered LDS + counted vmcnt(4) + raw barriers. 33.8KB LDS ->
// 2 INDEPENDENT blocks/CU (cross-block phase overlap; barriers no longer
// stall the whole CU as the round-5 8-wave block did).
// ---------------------------------------------------------------------------
__global__ __launch_bounds__(256, 2) void sims_filter_kernel(
    const float* __restrict__ qd, const unsigned char* __restrict__ dbb,
    unsigned long long* __restrict__ seg_g, unsigned int* __restrict__ cnt_g)
{
  __shared__ __align__(16) char db_lds[2][64 * 256];   // 2 x 16384 B (fp8)
  __shared__ int lcnt[4][64];                          // 1024 B (wave-private)

  const int tid  = (int)threadIdx.x;
  const int lane = tid & 63;
  const int wv   = tid >> 6;          // 0..3
  const int cid   = (int)blockIdx.x;  // 0..127
  const int mtile = (int)blockIdx.y;  // 0..3
  // chunks 0..53 have 25 subtiles, 54..127 have 24 (covers 3126 subtiles)
  const int nsub = 24 + (cid < 54 ? 1 : 0);
  const int row0 = (24*cid + (cid < 54 ? cid : 54)) << 6;

  lcnt[wv][lane] = 0;   // wave-private, no barrier needed

  const int l15  = lane & 15;
  const int egrp = lane >> 4;         // k-chunk group 0..3 (32 k each)
  const int rowb = egrp << 2;
  const int colb = l15;

  // ---- Q fragments: fp32 -> fp8 packed i32x8 (32 k-bytes/lane), per block ----
  i32x8 aq[4][2];
  {
    #pragma unroll
    for (int fm = 0; fm < 4; ++fm) {
      const float* qrow = qd + (size_t)(mtile*256 + wv*64 + fm*16 + l15)*CDIM;
      #pragma unroll
      for (int kk = 0; kk < 2; ++kk) {
        const float* p = qrow + kk*128 + egrp*32;
        i32x8 a;
        #pragma unroll
        for (int d = 0; d < 8; ++d) {
          float4 x = *(const float4*)(p + d*4);
          a[d] = (int)pk_fp8x4(x.x, x.y, x.z, x.w);
        }
        aq[fm][kk] = a;
      }
    }
  }

  const char* dbbase = (const char*)dbb;
#define STAGE(bufi, tile) do { \
    const char* _src = dbbase + ((size_t)(row0 + (tile)*64) * 256) + wv*4096 + lane*16; \
    char* _dst = (char*)db_lds[(bufi)] + wv*4096; \
    async_copy16(_src,        _dst); \
    async_copy16(_src + 1024, _dst + 1024); \
    async_copy16(_src + 2048, _dst + 2048); \
    async_copy16(_src + 3072, _dst + 3072); \
  } while (0)

  STAGE(0, 0);   // prologue: 4 loads outstanding per thread

  for (int s = 0; s < nsub; ++s) {
    // issue next tile into the other buffer, then wait ONLY for tile s
    // (earlier survivor stores are older in the vmem FIFO, so vmcnt(4)
    //  also proves them retired -- counting stays exact)
    if (s + 1 < nsub) {
      STAGE((s + 1) & 1, s + 1);
      asm volatile("s_waitcnt vmcnt(4)" ::: "memory");   // tile s resident
    } else {
      asm volatile("s_waitcnt vmcnt(0)" ::: "memory");   // last tile: full drain
    }
    __builtin_amdgcn_sched_barrier(0);
    __builtin_amdgcn_s_barrier();                        // block-local barrier
    __builtin_amdgcn_sched_barrier(0);

    // ---- MFMA: 64q x 64db, K=256 via 2x K=128 MX-fp8 (unit scale) ----
    f32x4 acc[4][4];
    #pragma unroll
    for (int fm = 0; fm < 4; ++fm)
      #pragma unroll
      for (int fn = 0; fn < 4; ++fn)
        acc[fm][fn] = (f32x4){0.f, 0.f, 0.f, 0.f};
    {
      const char* dbt = (const char*)db_lds[s & 1];
      #pragma unroll
      for (int kk = 0; kk < 2; ++kk) {
        #pragma unroll
        for (int fn = 0; fn < 4; ++fn) {
          const char* rowp = dbt + (fn*16 + l15)*256;
          const int mbase = kk*8 + egrp*2;
          i32x4 lo = *(const i32x4*)(rowp + (((mbase    ) ^ l15) << 4));
          i32x4 hi = *(const i32x4*)(rowp + (((mbase + 1) ^ l15) << 4));
          i32x8 b = __builtin_shufflevector(lo, hi, 0, 1, 2, 3, 4, 5, 6, 7);
          #pragma unroll
          for (int fm = 0; fm < 4; ++fm)
            acc[fm][fn] = __builtin_amdgcn_mfma_scale_f32_16x16x128_f8f6f4(
                aq[fm][kk], b, acc[fm][fn],
                0 /*fmtA=fp8*/, 0 /*fmtB=fp8*/,
                0, 0x7F7F7F7Fu /*scaleA=1.0*/, 0, 0x7F7F7F7Fu /*scaleB=1.0*/);
        }
      }
    }

    asm volatile("s_waitcnt lgkmcnt(0)" ::: "memory");   // own ds_reads done
    __builtin_amdgcn_sched_barrier(0);
    __builtin_amdgcn_s_barrier();                        // all waves done reading buf
    __builtin_amdgcn_sched_barrier(0);

    // ---- theta-filter on fragments; direct global survivor stores ----
    {
      const int idxbase = row0 + s*64;
      #pragma unroll
      for (int fm = 0; fm < 4; ++fm)
        #pragma unroll
        for (int fn = 0; fn < 4; ++fn) {
          const f32x4 a = acc[fm][fn];
          const float m = fmaxf(fmaxf(a[0], a[1]), fmaxf(a[2], a[3]));
          if (m > THETA) {
            #pragma unroll
            for (int j = 0; j < 4; ++j) {
              if (a[j] > THETA) {
                const int ql = fm*16 + rowb + j;
                const int slot = atomicAdd(&lcnt[wv][ql], 1);
                if (slot < CAPQ) {
                  const int qg = mtile*256 + wv*64 + ql;
                  const unsigned long long e =
                      (unsigned long long)__float_as_uint(a[j]) |
                      ((unsigned long long)(unsigned)(idxbase + fn*16 + colb) << 32);
                  seg_g[(size_t)(qg*NCH + cid)*CAPQ + slot] = e;
                }
              }
            }
          }
        }
    }
  }
#undef STAGE

  // ---- flush wave-private survivor counts ----
  asm volatile("s_waitcnt lgkmcnt(0)" ::: "memory");
  {
    const int qg = mtile*256 + wv*64 + lane;
    cnt_g[qg*NCH + cid] = (unsigned)lcnt[wv][lane];
  }
}

// ---------------------------------------------------------------------------
// Kernel 2: per-query gather of survivors -> exact top-16 -> vote.
// Self-check: overflow or <16 survivors -> set flag (triggers fallback).
// ---------------------------------------------------------------------------
__global__ __launch_bounds__(64) void gather_vote_kernel(
    const float* __restrict__ pdb,
    const unsigned long long* __restrict__ seg_g, const unsigned* __restrict__ cnt_g,
    int* __restrict__ out_label, float* __restrict__ out_s, int* __restrict__ flag)
{
  __shared__ float    cv[NCH*CAPQ];   // 1792
  __shared__ unsigned ci[NCH*CAPQ];
  const int q    = (int)blockIdx.x;
  const int lane = (int)threadIdx.x;

  bool over = false;
  int tot = 0;
  #pragma unroll
  for (int h = 0; h < 2; ++h) {
    const int c = h*64 + lane;
    const int cnt = (int)cnt_g[q*NCH + c];
    over |= (cnt > CAPQ);
    const int nc = min(cnt, CAPQ);
    tot += nc;
    const unsigned long long* src = seg_g + (size_t)(q*NCH + c)*CAPQ;
    for (int j = 0; j < CAPQ; ++j) {
      float v = NEGF; unsigned idx = 0u;
      if (j < nc) {
        const unsigned long long e = src[j];
        v = __uint_as_float((unsigned)e);
        idx = (unsigned)(e >> 32);
      }
      cv[c*CAPQ + j] = v;
      ci[c*CAPQ + j] = idx;
    }
  }
  #pragma unroll
  for (int off = 32; off >= 1; off >>= 1) tot += __shfl_xor(tot, off);
  __syncthreads();

  float topv[TK]; int topid[TK];
  #pragma unroll
  for (int r = 0; r < TK; ++r) {
    float bv = NEGF; int bp = -1;
    #pragma unroll 4
    for (int j = 0; j < (NCH*CAPQ)/64; ++j) {
      const int p = j*64 + lane;
      const float v = cv[p];
      if (v > bv) { bv = v; bp = p; }
    }
    #pragma unroll
    for (int off = 32; off >= 1; off >>= 1) {
      const float ov = __shfl_xor(bv, off);
      const int   op = __shfl_xor(bp, off);
      if (ov > bv || (ov == bv && ((unsigned)op < (unsigned)bp))) { bv = ov; bp = op; }
    }
    topv[r] = bv;
    int id = -2;
    if (bp >= 0 && bv > NEGF) id = (int)pdb[(size_t)ci[bp]*PDBW + CDIM];
    topid[r] = id;
    if (lane == 0 && bp >= 0) cv[bp] = NEGF;
    __syncthreads();
  }

  if (lane == 0) {
    bool mk[TK];
    int nvalid = 0;
    #pragma unroll
    for (int i = 0; i < TK; ++i) {
      mk[i] = (topv[i] >= MIN_SIM_C) && (topid[i] >= 0);
      nvalid += mk[i] ? 1 : 0;
    }
    int maj = 0, majid = 0x7fffffff;
    for (int i = 0; i < TK; ++i) {
      if (!mk[i]) continue;
      int c = 0;
      for (int j = 0; j < TK; ++j) c += (mk[j] && topid[j] == topid[i]) ? 1 : 0;
      if (c > maj || (c == maj && topid[i] < majid)) { maj = c; majid = topid[i]; }
    }
    const float ratio = (float)maj / fmaxf((float)nvalid, 1.0f);
    const bool valid = (maj > 0) && (ratio >= MIN_VOTES_C);
    const int label = valid ? majid : -1;
    float s = 0.f;
    #pragma unroll
    for (int i = 0; i < TK; ++i)
      if (mk[i] && topid[i] == label) s = fmaxf(s, topv[i]);
    out_label[q] = label;
    out_s[q]     = s;
  }
  const bool bad = (__ballot(over) != 0ull) || (tot < TK);
  if (lane == 0 && bad) atomicOr(flag, 1);
}

// ---------------------------------------------------------------------------
// Fallback stage 1 (round-1, proven): gated on flag
// ---------------------------------------------------------------------------
__global__ __launch_bounds__(256, 2) void sims_topk1_kernel(
    const float* __restrict__ qd, const float* __restrict__ pdb,
    float* __restrict__ cand_val, unsigned int* __restrict__ cand_idx,
    const int* __restrict__ gate)
{
  if (gate && *gate == 0) return;
  __shared__ __align__(16) short db_lds[128 * 264];
  float* sims = (float*)db_lds;

  const int tid  = (int)threadIdx.x;
  const int lane = tid & 63;
  const int wv   = tid >> 6;
  const int cid   = (int)blockIdx.x;
  const int mtile = (int)blockIdx.y;

  bf16x8 aq[2][8];
  {
    const int l15 = lane & 15;
    const int kb  = (lane >> 4) << 3;
    #pragma unroll
    for (int fm = 0; fm < 2; ++fm) {
      const int row = mtile*128 + wv*32 + fm*16 + l15;
      #pragma unroll
      for (int kk = 0; kk < 8; ++kk) {
        const float* p = qd + (size_t)row*CDIM + kk*32 + kb;
        float4 x0 = *(const float4*)p;
        float4 x1 = *(const float4*)(p + 4);
        bf16x8 a;
        a[0]=f2bf(x0.x); a[1]=f2bf(x0.y); a[2]=f2bf(x0.z); a[3]=f2bf(x0.w);
        a[4]=f2bf(x1.x); a[5]=f2bf(x1.y); a[6]=f2bf(x1.z); a[7]=f2bf(x1.w);
        aq[fm][kk] = a;
      }
    }
  }

  float    tv[TK];
  unsigned ti[TK];
  #pragma unroll
  for (int i = 0; i < TK; ++i) { tv[i] = NEGF; ti[i] = 0u; }
  float minv = NEGF; int minp = 0;

  const int g0chunk = cid * 4096;
  const int q_l  = tid & 127;
  const int half = tid >> 7;

  for (int s = 0; s < 32; ++s) {
    const int g0 = g0chunk + s*128;
    {
      const int rb = tid >> 6;
      const int c4 = (tid & 63) << 2;
      for (int i = 0; i < 32; ++i) {
        const int rl = i*4 + rb;
        const int g  = g0 + rl;
        float v0, v1, v2, v3;
        if (g < NDB) {
          const float* p = pdb + (size_t)g*PDBW + c4;
          v0 = p[0]; v1 = p[1]; v2 = p[2]; v3 = p[3];
        } else { v0 = v1 = v2 = v3 = 0.f; }
        short* d = &db_lds[rl*264 + c4];
        d[0]=f2bf(v0); d[1]=f2bf(v1); d[2]=f2bf(v2); d[3]=f2bf(v3);
      }
    }
    __syncthreads();

    f32x4 acc[2][8];
    #pragma unroll
    for (int fm = 0; fm < 2; ++fm)
      #pragma unroll
      for (int fn = 0; fn < 8; ++fn)
        acc[fm][fn] = (f32x4){0.f, 0.f, 0.f, 0.f};
    {
      const int l15 = lane & 15;
      const int kb  = (lane >> 4) << 3;
      #pragma unroll
      for (int kk = 0; kk < 8; ++kk) {
        bf16x8 b[8];
        #pragma unroll
        for (int fn = 0; fn < 8; ++fn)
          b[fn] = *(const bf16x8*)&db_lds[(fn*16 + l15)*264 + kk*32 + kb];
        #pragma unroll
        for (int fn = 0; fn < 8; ++fn) {
          acc[0][fn] = __builtin_amdgcn_mfma_f32_16x16x32_bf16(aq[0][kk], b[fn], acc[0][fn], 0, 0, 0);
          acc[1][fn] = __builtin_amdgcn_mfma_f32_16x16x32_bf16(aq[1][kk], b[fn], acc[1][fn], 0, 0, 0);
        }
      }
    }
    __syncthreads();

    {
      const int colb = lane & 15;
      const int rowb = (lane >> 4) << 2;
      #pragma unroll
      for (int fm = 0; fm < 2; ++fm)
        #pragma unroll
        for (int fn = 0; fn < 8; ++fn)
          #pragma unroll
          for (int j = 0; j < 4; ++j)
            sims[(wv*32 + fm*16 + rowb + j)*129 + fn*16 + colb] = acc[fm][fn][j];
    }
    __syncthreads();

    {
      const int cb = half * 64;
      #pragma unroll 4
      for (int c = 0; c < 64; ++c) {
        const int colc = cb + c;
        const float v = sims[q_l*129 + colc];
        const int g = g0 + colc;
        if (v > minv && g < NDB) {
          #pragma unroll
          for (int i = 0; i < TK; ++i) if (i == minp) { tv[i] = v; ti[i] = (unsigned)g; }
          minv = tv[0]; minp = 0;
          #pragma unroll
          for (int i = 1; i < TK; ++i) if (tv[i] < minv) { minv = tv[i]; minp = i; }
        }
      }
    }
    __syncthreads();
  }

  {
    const int qg = mtile*128 + q_l;
    float*    pv = cand_val + ((size_t)qg*NCHUNK1 + cid)*32 + half*TK;
    unsigned* pi = cand_idx + ((size_t)qg*NCHUNK1 + cid)*32 + half*TK;
    #pragma unroll
    for (int i = 0; i < TK; ++i) { pv[i] = tv[i]; pi[i] = ti[i]; }
  }
}

// ---------------------------------------------------------------------------
// Fallback stage 2 (round-1, proven): gated on flag
// ---------------------------------------------------------------------------
template<int CPQ>
__global__ __launch_bounds__(64) void merge_vote_kernel(
    const float* __restrict__ pdb,
    const float* __restrict__ cand_val, const unsigned* __restrict__ cand_idx,
    int* __restrict__ out_label, float* __restrict__ out_s,
    const int* __restrict__ gate)
{
  if (gate && *gate == 0) return;
  __shared__ float    cv[CPQ];
  __shared__ unsigned ci[CPQ];
  const int q    = (int)blockIdx.x;
  const int lane = (int)threadIdx.x;

  for (int j = lane; j < CPQ; j += 64) {
    cv[j] = cand_val[(size_t)q*CPQ + j];
    ci[j] = cand_idx[(size_t)q*CPQ + j];
  }
  __syncthreads();

  float topv[TK]; int topid[TK];
  #pragma unroll
  for (int r = 0; r < TK; ++r) {
    float bv = NEGF; int bp = -1;
    for (int j = lane; j < CPQ; j += 64) {
      const float v = cv[j];
      if (v > bv) { bv = v; bp = j; }
    }
    #pragma unroll
    for (int off = 32; off >= 1; off >>= 1) {
      const float ov = __shfl_xor(bv, off);
      const int   op = __shfl_xor(bp, off);
      if (ov > bv || (ov == bv && ((unsigned)op < (unsigned)bp))) { bv = ov; bp = op; }
    }
    topv[r] = bv;
    int id = -2;
    if (bp >= 0 && bv > NEGF) id = (int)pdb[(size_t)ci[bp]*PDBW + CDIM];
    topid[r] = id;
    if (lane == 0 && bp >= 0) cv[bp] = NEGF;
    __syncthreads();
  }

  if (lane == 0) {
    bool mk[TK];
    int nvalid = 0;
    #pragma unroll
    for (int i = 0; i < TK; ++i) {
      mk[i] = (topv[i] >= MIN_SIM_C) && (topid[i] >= 0);
      nvalid += mk[i] ? 1 : 0;
    }
    int maj = 0, majid = 0x7fffffff;
    for (int i = 0; i < TK; ++i) {
      if (!mk[i]) continue;
      int c = 0;
      for (int j = 0; j < TK; ++j) c += (mk[j] && topid[j] == topid[i]) ? 1 : 0;
      if (c > maj || (c == maj && topid[i] < majid)) { maj = c; majid = topid[i]; }
    }
    const float ratio = (float)maj / fmaxf((float)nvalid, 1.0f);
    const bool valid = (maj > 0) && (ratio >= MIN_VOTES_C);
    const int label = valid ? majid : -1;
    float s = 0.f;
    #pragma unroll
    for (int i = 0; i < TK; ++i)
      if (mk[i] && topid[i] == label) s = fmaxf(s, topv[i]);
    out_label[q] = label;
    out_s[q]     = s;
  }
}

// ---------------------------------------------------------------------------
// Stage 3: overlap removal + final outputs
// ---------------------------------------------------------------------------
__device__ __forceinline__ bool finitef(float v) {
  return ((__float_as_uint(v) >> 23) & 0xffu) != 0xffu;
}

__global__ __launch_bounds__(64) void finalize_kernel(
    const float* __restrict__ boxes, const int* __restrict__ labels,
    const float* __restrict__ svals, float* __restrict__ out)
{
  const int x    = (int)blockIdx.x;
  const int lane = (int)threadIdx.x;
  const int lx = labels[x];
  const float bx1 = boxes[x*4+0], by1 = boxes[x*4+1];
  const float bx2 = boxes[x*4+2], by2 = boxes[x*4+3];
  const float ax = (bx2 - bx1) * (by2 - by1);

  bool flag = false;
  if (lx >= 0) {
    for (int y = lane; y < QN; y += 64) {
      if (y == x) continue;
      if (labels[y] != lx) continue;
      const float c1 = boxes[y*4+0], c2 = boxes[y*4+1];
      const float c3 = boxes[y*4+2], c4 = boxes[y*4+3];
      const float ay = (c3 - c1) * (c4 - c2);
      const float xi1 = fmaxf(bx1, c1), yi1 = fmaxf(by1, c2);
      const float xi2 = fminf(bx2, c3), yi2 = fminf(by2, c4);
      const float inter = fmaxf(xi2 - xi1, 0.f) * fmaxf(yi2 - yi1, 0.f);
      const float asmall = fminf(ax, ay);
      const float ov = (asmall > 0.f) ? inter / fmaxf(asmall, 1e-12f) : 0.f;
      if (ov >= 0.5f && ay <= ax) flag = true;
    }
  }
  const bool removed = (__ballot(flag) != 0ull);
  const int label = removed ? -1 : lx;
  const float s = svals[x];
  const bool fin = finitef(s) && finitef(bx1) && finitef(by1) && finitef(bx2) && finitef(by2);
  const bool valid = (label >= 0) && fin;

  if (lane == 0) {
    out[4096 + x] = valid ? s : 0.f;
    out[5120 + x] = (float)(valid ? label : -1);
  }
  if (lane < 4) out[x*4 + lane] = boxes[x*4 + lane];
}

// ---------------------------------------------------------------------------
extern "C" void kernel_launch(void* const* d_in, const int* in_sizes, int n_in,
                              void* d_out, int out_size, void* d_ws, size_t ws_size,
                              hipStream_t stream)
{
  const float* boxes = (const float*)d_in[0];
  const float* qd    = (const float*)d_in[1];
  const float* pdb   = (const float*)d_in[2];
  float* out = (float*)d_out;
  char* ws = (char*)d_ws;

  const size_t db_bytes  = (size_t)NDB_PAD * 256;             //  51,216,384 (fp8)
  const size_t seg_bytes = (size_t)QN * NCH * CAPQ * 8;       //  14,680,064
  const size_t cnt_bytes = (size_t)QN * NCH * 4;              //     524,288
  const size_t c1_bytes  = (size_t)QN * CPQ1 * 8;             //  12,845,056 (fallback, aliases seg+cnt)
  const size_t A_bytes   = (seg_bytes + cnt_bytes > c1_bytes) ? seg_bytes + cnt_bytes : c1_bytes;
  const size_t need = db_bytes + A_bytes + (size_t)QN*8 + 64;

  if (ws_size >= need) {
    unsigned char* dbb = (unsigned char*)ws;
    char* A = ws + db_bytes;
    unsigned long long* seg_g = (unsigned long long*)A;
    unsigned*           cnt_g = (unsigned*)(A + seg_bytes);
    float*    cand_val = (float*)A;
    unsigned* cand_idx = (unsigned*)(A + (size_t)QN*CPQ1*4);
    int*      labels   = (int*)(ws + db_bytes + A_bytes);
    float*    svals    = (float*)(ws + db_bytes + A_bytes + (size_t)QN*4);
    int*      flag     = (int*)(ws + db_bytes + A_bytes + (size_t)QN*8);

    hipMemsetAsync(flag, 0, 4, stream);
    hipLaunchKernelGGL(convert_db_kernel, dim3(2048), dim3(256), 0, stream, pdb, dbb);
    hipLaunchKernelGGL(sims_filter_kernel, dim3(NCH, 4), dim3(256), 0, stream,
                       qd, dbb, seg_g, cnt_g);
    hipLaunchKernelGGL(gather_vote_kernel, dim3(QN), dim3(64), 0, stream,
                       pdb, seg_g, cnt_g, labels, svals, flag);
    hipLaunchKernelGGL(sims_topk1_kernel, dim3(NCHUNK1, 8), dim3(256), 0, stream,
                       qd, pdb, cand_val, cand_idx, flag);
    hipLaunchKernelGGL((merge_vote_kernel<CPQ1>), dim3(QN), dim3(64), 0, stream,
                       pdb, cand_val, cand_idx, labels, svals, flag);
    hipLaunchKernelGGL(finalize_kernel, dim3(QN), dim3(64), 0, stream,
                       boxes, labels, svals, out);
  } else {
    const size_t n1 = (size_t)QN * CPQ1;
    float*    cand_val = (float*)ws;
    unsigned* cand_idx = (unsigned*)(ws + n1*4);
    int*      labels   = (int*)(ws + n1*8);
    float*    svals    = (float*)(ws + n1*8 + (size_t)QN*4);

    hipLaunchKernelGGL(sims_topk1_kernel, dim3(NCHUNK1, 8), dim3(256), 0, stream,
                       qd, pdb, cand_val, cand_idx, (const int*)nullptr);
    hipLaunchKernelGGL((merge_vote_kernel<CPQ1>), dim3(QN), dim3(64), 0, stream,
                       pdb, cand_val, cand_idx, labels, svals, (const int*)nullptr);
    hipLaunchKernelGGL(finalize_kernel, dim3(QN), dim3(64), 0, stream,
                       boxes, labels, svals, out);
  }
}

// Round 7
// 174.378 us; speedup vs baseline: 1.4685x; 1.0219x over previous
//
#include <hip/hip_runtime.h>
#include <hip/hip_bf16.h>

// ---------------- problem constants ----------------
#define QN 1024
#define NDB 200000
#define NDB_PAD 200064        // 3126 subtiles of 64 rows
#define PDBW 257
#define CDIM 256
#define TK 16
#define NEGF (-1e30f)
#define MIN_SIM_C 0.05f
#define MIN_VOTES_C 0.3f

// fast path: 128 chunks x 4 query-tiles (256 q/block, 4 waves); MX-fp8 filter
#define NCH 128
#define THETA 0.19f           // P(sim>THETA)=1.18e-3; true 16th-best ~0.236 (fp8 err ~3e-3 -> ~15 sigma)
#define CAPQ 14               // per-(query,chunk) cap (lambda~1.84, P(over)~1e-9/cell)
// fallback (round-1, proven) path
#define NCHUNK1 49
#define CPQ1 (NCHUNK1*32)

typedef __attribute__((ext_vector_type(8))) short bf16x8;
typedef __attribute__((ext_vector_type(4))) float f32x4;
typedef __attribute__((ext_vector_type(8))) int   i32x8;
typedef __attribute__((ext_vector_type(4))) int   i32x4;

__device__ __forceinline__ short f2bf(float f) {
  union { float f; unsigned u; } x; x.f = f;
  unsigned u = x.u;
  return (short)((u + 0x7fffu + ((u >> 16) & 1u)) >> 16);  // RNE
}

__device__ __forceinline__ void async_copy16(const void* gp, void* lp) {
  __builtin_amdgcn_global_load_lds(
      (__attribute__((address_space(1))) void*)gp,
      (__attribute__((address_space(3))) void*)lp, 16, 0, 0);
}

// pack 4 floats -> 4 fp8 e4m3 bytes (same converter feeds A and B, so any
// consistent lane-position->k mapping cancels in the MFMA dot product)
__device__ __forceinline__ unsigned pk_fp8x4(float a, float b, float c, float d) {
  unsigned w = (unsigned)__builtin_amdgcn_cvt_pk_fp8_f32(a, b, 0, false);
  w = (unsigned)__builtin_amdgcn_cvt_pk_fp8_f32(c, d, (int)w, true);
  return w;
}

// ---------------------------------------------------------------------------
// Kernel 0: pdb fp32 -> fp8 e4m3, 16B-pair swizzle (pair m -> m ^ (r&15)),
// zero-pad rows [NDB, NDB_PAD). One wave per row; lane covers 4 elems.
// ---------------------------------------------------------------------------
__global__ __launch_bounds__(256) void convert_db_kernel(
    const float* __restrict__ pdb, unsigned char* __restrict__ dbb)
{
  const int wv = (int)threadIdx.x >> 6, lane = (int)threadIdx.x & 63;
  for (int r = (int)blockIdx.x*4 + wv; r < NDB_PAD; r += (int)gridDim.x*4) {
    unsigned pack = 0u;
    if (r < NDB) {
      const float* p = pdb + (size_t)r*PDBW + lane*4;
      pack = pk_fp8x4(p[0], p[1], p[2], p[3]);
    }
    const int piece = lane >> 1;                       // 8B piece index 0..31
    const int ps    = piece ^ ((r & 15) << 1);         // == 16B-pair ^ (r&15)
    *(unsigned*)(dbb + (size_t)r*256 + ps*8 + (lane & 1)*4) = pack;
  }
}

// ---------------------------------------------------------------------------
// Kernel 1: MX-fp8 (K=128, unit scale) MFMA sims + register theta-filter +
// wave-private LDS survivor lists (flushed once after the loop; the main
// loop issues NO global ops except the staging DMA).
// grid (128, 4), 256 thr (4 waves x 64 queries). Subtile = 64 db rows (16KB).
// ONE barrier per subtile: lgkm-drain at iteration end guarantees all waves
// finished reading tile s-1 before the barrier, so STAGE(s+1) issued after
// the barrier can overwrite that buffer; its DMA hides under MFMA+filter.
// 61KB LDS -> 2 independent blocks/CU (cross-block overlap at barriers).
// ---------------------------------------------------------------------------
__global__ __launch_bounds__(256, 2) void sims_filter_kernel(
    const float* __restrict__ qd, const unsigned char* __restrict__ dbb,
    unsigned long long* __restrict__ seg_g, unsigned int* __restrict__ cnt_g)
{
  __shared__ __align__(16) char db_lds[2][64 * 256];   // 2 x 16384 B (fp8)
  __shared__ unsigned seg_lds[4][64][CAPQ][2];         // 28672 B (wave-private)
  __shared__ int lcnt[4][64];                          // 1024 B (wave-private)

  const int tid  = (int)threadIdx.x;
  const int lane = tid & 63;
  const int wv   = tid >> 6;          // 0..3
  const int cid   = (int)blockIdx.x;  // 0..127
  const int mtile = (int)blockIdx.y;  // 0..3
  // chunks 0..53 have 25 subtiles, 54..127 have 24 (covers 3126 subtiles)
  const int nsub = 24 + (cid < 54 ? 1 : 0);
  const int row0 = (24*cid + (cid < 54 ? cid : 54)) << 6;

  lcnt[wv][lane] = 0;   // wave-private, no barrier needed

  const int l15  = lane & 15;
  const int egrp = lane >> 4;         // k-chunk group 0..3 (32 k each)
  const int rowb = egrp << 2;
  const int colb = l15;

  // ---- Q fragments: fp32 -> fp8 packed i32x8 (32 k-bytes/lane), per block ----
  i32x8 aq[4][2];
  {
    #pragma unroll
    for (int fm = 0; fm < 4; ++fm) {
      const float* qrow = qd + (size_t)(mtile*256 + wv*64 + fm*16 + l15)*CDIM;
      #pragma unroll
      for (int kk = 0; kk < 2; ++kk) {
        const float* p = qrow + kk*128 + egrp*32;
        i32x8 a;
        #pragma unroll
        for (int d = 0; d < 8; ++d) {
          float4 x = *(const float4*)(p + d*4);
          a[d] = (int)pk_fp8x4(x.x, x.y, x.z, x.w);
        }
        aq[fm][kk] = a;
      }
    }
  }

  const char* dbbase = (const char*)dbb;
#define STAGE(bufi, tile) do { \
    const char* _src = dbbase + ((size_t)(row0 + (tile)*64) * 256) + wv*4096 + lane*16; \
    char* _dst = (char*)db_lds[(bufi)] + wv*4096; \
    async_copy16(_src,        _dst); \
    async_copy16(_src + 1024, _dst + 1024); \
    async_copy16(_src + 2048, _dst + 2048); \
    async_copy16(_src + 3072, _dst + 3072); \
  } while (0)

  STAGE(0, 0);   // prologue: 4 loads outstanding per thread

  for (int s = 0; s < nsub; ++s) {
    // tile s's loads were issued a full iteration ago (prologue for s=0);
    // the vmem queue holds nothing else -> this drain is ~instant
    asm volatile("s_waitcnt vmcnt(0)" ::: "memory");
    __builtin_amdgcn_sched_barrier(0);
    __builtin_amdgcn_s_barrier();       // ONE barrier: tile s visible to all;
                                        // all waves' tile-(s-1) reads drained
    __builtin_amdgcn_sched_barrier(0);

    // issue next tile into the other buffer NOW (overwrites tile s-1 -- safe;
    // DMA latency hides under the ~2000-cyc MFMA+filter phase below)
    if (s + 1 < nsub) STAGE((s + 1) & 1, s + 1);

    // ---- MFMA: 64q x 64db, K=256 via 2x K=128 MX-fp8 (unit scale) ----
    f32x4 acc[4][4];
    #pragma unroll
    for (int fm = 0; fm < 4; ++fm)
      #pragma unroll
      for (int fn = 0; fn < 4; ++fn)
        acc[fm][fn] = (f32x4){0.f, 0.f, 0.f, 0.f};
    __builtin_amdgcn_s_setprio(1);
    {
      const char* dbt = (const char*)db_lds[s & 1];
      #pragma unroll
      for (int kk = 0; kk < 2; ++kk) {
        #pragma unroll
        for (int fn = 0; fn < 4; ++fn) {
          const char* rowp = dbt + (fn*16 + l15)*256;
          const int mbase = kk*8 + egrp*2;
          i32x4 lo = *(const i32x4*)(rowp + (((mbase    ) ^ l15) << 4));
          i32x4 hi = *(const i32x4*)(rowp + (((mbase + 1) ^ l15) << 4));
          i32x8 b = __builtin_shufflevector(lo, hi, 0, 1, 2, 3, 4, 5, 6, 7);
          #pragma unroll
          for (int fm = 0; fm < 4; ++fm)
            acc[fm][fn] = __builtin_amdgcn_mfma_scale_f32_16x16x128_f8f6f4(
                aq[fm][kk], b, acc[fm][fn],
                0 /*fmtA=fp8*/, 0 /*fmtB=fp8*/,
                0, 0x7F7F7F7Fu /*scaleA=1.0*/, 0, 0x7F7F7F7Fu /*scaleB=1.0*/);
        }
      }
    }
    __builtin_amdgcn_s_setprio(0);

    // ---- theta-filter on fragments; wave-private LDS append (lgkm domain,
    //      never touches the vmem prefetch queue) ----
    {
      const int idxbase = row0 + s*64;
      #pragma unroll
      for (int fm = 0; fm < 4; ++fm)
        #pragma unroll
        for (int fn = 0; fn < 4; ++fn) {
          const f32x4 a = acc[fm][fn];
          const float m = fmaxf(fmaxf(a[0], a[1]), fmaxf(a[2], a[3]));
          if (m > THETA) {
            #pragma unroll
            for (int j = 0; j < 4; ++j) {
              if (a[j] > THETA) {
                const int ql = fm*16 + rowb + j;
                const int slot = atomicAdd(&lcnt[wv][ql], 1);
                if (slot < CAPQ) {
                  seg_lds[wv][ql][slot][0] = __float_as_uint(a[j]);
                  seg_lds[wv][ql][slot][1] = (unsigned)(idxbase + fn*16 + colb);
                }
              }
            }
          }
        }
    }

    // drain own ds_reads + LDS atomics before the next barrier (this is what
    // makes the single-barrier buffer-reuse hazard-free)
    asm volatile("s_waitcnt lgkmcnt(0)" ::: "memory");
    __builtin_amdgcn_sched_barrier(0);
  }
#undef STAGE

  // ---- flush wave-private survivor lists to global (lane == local query) ----
  {
    const int cnt = lcnt[wv][lane];
    const int qg = mtile*256 + wv*64 + lane;
    cnt_g[qg*NCH + cid] = (unsigned)cnt;
    const int nc = min(cnt, CAPQ);
    unsigned long long* dst = seg_g + (size_t)(qg*NCH + cid)*CAPQ;
    for (int j = 0; j < nc; ++j) {
      unsigned long long lo = seg_lds[wv][lane][j][0];
      unsigned long long hi = seg_lds[wv][lane][j][1];
      dst[j] = lo | (hi << 32);
    }
  }
}

// ---------------------------------------------------------------------------
// Kernel 2: per-query gather of survivors -> exact top-16 -> vote.
// Self-check: overflow or <16 survivors -> set flag (triggers fallback).
// ---------------------------------------------------------------------------
__global__ __launch_bounds__(64) void gather_vote_kernel(
    const float* __restrict__ pdb,
    const unsigned long long* __restrict__ seg_g, const unsigned* __restrict__ cnt_g,
    int* __restrict__ out_label, float* __restrict__ out_s, int* __restrict__ flag)
{
  __shared__ float    cv[NCH*CAPQ];   // 1792
  __shared__ unsigned ci[NCH*CAPQ];
  const int q    = (int)blockIdx.x;
  const int lane = (int)threadIdx.x;

  bool over = false;
  int tot = 0;
  #pragma unroll
  for (int h = 0; h < 2; ++h) {
    const int c = h*64 + lane;
    const int cnt = (int)cnt_g[q*NCH + c];
    over |= (cnt > CAPQ);
    const int nc = min(cnt, CAPQ);
    tot += nc;
    const unsigned long long* src = seg_g + (size_t)(q*NCH + c)*CAPQ;
    for (int j = 0; j < CAPQ; ++j) {
      float v = NEGF; unsigned idx = 0u;
      if (j < nc) {
        const unsigned long long e = src[j];
        v = __uint_as_float((unsigned)e);
        idx = (unsigned)(e >> 32);
      }
      cv[c*CAPQ + j] = v;
      ci[c*CAPQ + j] = idx;
    }
  }
  #pragma unroll
  for (int off = 32; off >= 1; off >>= 1) tot += __shfl_xor(tot, off);
  __syncthreads();

  float topv[TK]; int topid[TK];
  #pragma unroll
  for (int r = 0; r < TK; ++r) {
    float bv = NEGF; int bp = -1;
    #pragma unroll 4
    for (int j = 0; j < (NCH*CAPQ)/64; ++j) {
      const int p = j*64 + lane;
      const float v = cv[p];
      if (v > bv) { bv = v; bp = p; }
    }
    #pragma unroll
    for (int off = 32; off >= 1; off >>= 1) {
      const float ov = __shfl_xor(bv, off);
      const int   op = __shfl_xor(bp, off);
      if (ov > bv || (ov == bv && ((unsigned)op < (unsigned)bp))) { bv = ov; bp = op; }
    }
    topv[r] = bv;
    int id = -2;
    if (bp >= 0 && bv > NEGF) id = (int)pdb[(size_t)ci[bp]*PDBW + CDIM];
    topid[r] = id;
    if (lane == 0 && bp >= 0) cv[bp] = NEGF;
    __syncthreads();
  }

  if (lane == 0) {
    bool mk[TK];
    int nvalid = 0;
    #pragma unroll
    for (int i = 0; i < TK; ++i) {
      mk[i] = (topv[i] >= MIN_SIM_C) && (topid[i] >= 0);
      nvalid += mk[i] ? 1 : 0;
    }
    int maj = 0, majid = 0x7fffffff;
    for (int i = 0; i < TK; ++i) {
      if (!mk[i]) continue;
      int c = 0;
      for (int j = 0; j < TK; ++j) c += (mk[j] && topid[j] == topid[i]) ? 1 : 0;
      if (c > maj || (c == maj && topid[i] < majid)) { maj = c; majid = topid[i]; }
    }
    const float ratio = (float)maj / fmaxf((float)nvalid, 1.0f);
    const bool valid = (maj > 0) && (ratio >= MIN_VOTES_C);
    const int label = valid ? majid : -1;
    float s = 0.f;
    #pragma unroll
    for (int i = 0; i < TK; ++i)
      if (mk[i] && topid[i] == label) s = fmaxf(s, topv[i]);
    out_label[q] = label;
    out_s[q]     = s;
  }
  const bool bad = (__ballot(over) != 0ull) || (tot < TK);
  if (lane == 0 && bad) atomicOr(flag, 1);
}

// ---------------------------------------------------------------------------
// Fallback stage 1 (round-1, proven): gated on flag
// ---------------------------------------------------------------------------
__global__ __launch_bounds__(256, 2) void sims_topk1_kernel(
    const float* __restrict__ qd, const float* __restrict__ pdb,
    float* __restrict__ cand_val, unsigned int* __restrict__ cand_idx,
    const int* __restrict__ gate)
{
  if (gate && *gate == 0) return;
  __shared__ __align__(16) short db_lds[128 * 264];
  float* sims = (float*)db_lds;

  const int tid  = (int)threadIdx.x;
  const int lane = tid & 63;
  const int wv   = tid >> 6;
  const int cid   = (int)blockIdx.x;
  const int mtile = (int)blockIdx.y;

  bf16x8 aq[2][8];
  {
    const int l15 = lane & 15;
    const int kb  = (lane >> 4) << 3;
    #pragma unroll
    for (int fm = 0; fm < 2; ++fm) {
      const int row = mtile*128 + wv*32 + fm*16 + l15;
      #pragma unroll
      for (int kk = 0; kk < 8; ++kk) {
        const float* p = qd + (size_t)row*CDIM + kk*32 + kb;
        float4 x0 = *(const float4*)p;
        float4 x1 = *(const float4*)(p + 4);
        bf16x8 a;
        a[0]=f2bf(x0.x); a[1]=f2bf(x0.y); a[2]=f2bf(x0.z); a[3]=f2bf(x0.w);
        a[4]=f2bf(x1.x); a[5]=f2bf(x1.y); a[6]=f2bf(x1.z); a[7]=f2bf(x1.w);
        aq[fm][kk] = a;
      }
    }
  }

  float    tv[TK];
  unsigned ti[TK];
  #pragma unroll
  for (int i = 0; i < TK; ++i) { tv[i] = NEGF; ti[i] = 0u; }
  float minv = NEGF; int minp = 0;

  const int g0chunk = cid * 4096;
  const int q_l  = tid & 127;
  const int half = tid >> 7;

  for (int s = 0; s < 32; ++s) {
    const int g0 = g0chunk + s*128;
    {
      const int rb = tid >> 6;
      const int c4 = (tid & 63) << 2;
      for (int i = 0; i < 32; ++i) {
        const int rl = i*4 + rb;
        const int g  = g0 + rl;
        float v0, v1, v2, v3;
        if (g < NDB) {
          const float* p = pdb + (size_t)g*PDBW + c4;
          v0 = p[0]; v1 = p[1]; v2 = p[2]; v3 = p[3];
        } else { v0 = v1 = v2 = v3 = 0.f; }
        short* d = &db_lds[rl*264 + c4];
        d[0]=f2bf(v0); d[1]=f2bf(v1); d[2]=f2bf(v2); d[3]=f2bf(v3);
      }
    }
    __syncthreads();

    f32x4 acc[2][8];
    #pragma unroll
    for (int fm = 0; fm < 2; ++fm)
      #pragma unroll
      for (int fn = 0; fn < 8; ++fn)
        acc[fm][fn] = (f32x4){0.f, 0.f, 0.f, 0.f};
    {
      const int l15 = lane & 15;
      const int kb  = (lane >> 4) << 3;
      #pragma unroll
      for (int kk = 0; kk < 8; ++kk) {
        bf16x8 b[8];
        #pragma unroll
        for (int fn = 0; fn < 8; ++fn)
          b[fn] = *(const bf16x8*)&db_lds[(fn*16 + l15)*264 + kk*32 + kb];
        #pragma unroll
        for (int fn = 0; fn < 8; ++fn) {
          acc[0][fn] = __builtin_amdgcn_mfma_f32_16x16x32_bf16(aq[0][kk], b[fn], acc[0][fn], 0, 0, 0);
          acc[1][fn] = __builtin_amdgcn_mfma_f32_16x16x32_bf16(aq[1][kk], b[fn], acc[1][fn], 0, 0, 0);
        }
      }
    }
    __syncthreads();

    {
      const int colb = lane & 15;
      const int rowb = (lane >> 4) << 2;
      #pragma unroll
      for (int fm = 0; fm < 2; ++fm)
        #pragma unroll
        for (int fn = 0; fn < 8; ++fn)
          #pragma unroll
          for (int j = 0; j < 4; ++j)
            sims[(wv*32 + fm*16 + rowb + j)*129 + fn*16 + colb] = acc[fm][fn][j];
    }
    __syncthreads();

    {
      const int cb = half * 64;
      #pragma unroll 4
      for (int c = 0; c < 64; ++c) {
        const int colc = cb + c;
        const float v = sims[q_l*129 + colc];
        const int g = g0 + colc;
        if (v > minv && g < NDB) {
          #pragma unroll
          for (int i = 0; i < TK; ++i) if (i == minp) { tv[i] = v; ti[i] = (unsigned)g; }
          minv = tv[0]; minp = 0;
          #pragma unroll
          for (int i = 1; i < TK; ++i) if (tv[i] < minv) { minv = tv[i]; minp = i; }
        }
      }
    }
    __syncthreads();
  }

  {
    const int qg = mtile*128 + q_l;
    float*    pv = cand_val + ((size_t)qg*NCHUNK1 + cid)*32 + half*TK;
    unsigned* pi = cand_idx + ((size_t)qg*NCHUNK1 + cid)*32 + half*TK;
    #pragma unroll
    for (int i = 0; i < TK; ++i) { pv[i] = tv[i]; pi[i] = ti[i]; }
  }
}

// ---------------------------------------------------------------------------
// Fallback stage 2 (round-1, proven): gated on flag
// ---------------------------------------------------------------------------
template<int CPQ>
__global__ __launch_bounds__(64) void merge_vote_kernel(
    const float* __restrict__ pdb,
    const float* __restrict__ cand_val, const unsigned* __restrict__ cand_idx,
    int* __restrict__ out_label, float* __restrict__ out_s,
    const int* __restrict__ gate)
{
  if (gate && *gate == 0) return;
  __shared__ float    cv[CPQ];
  __shared__ unsigned ci[CPQ];
  const int q    = (int)blockIdx.x;
  const int lane = (int)threadIdx.x;

  for (int j = lane; j < CPQ; j += 64) {
    cv[j] = cand_val[(size_t)q*CPQ + j];
    ci[j] = cand_idx[(size_t)q*CPQ + j];
  }
  __syncthreads();

  float topv[TK]; int topid[TK];
  #pragma unroll
  for (int r = 0; r < TK; ++r) {
    float bv = NEGF; int bp = -1;
    for (int j = lane; j < CPQ; j += 64) {
      const float v = cv[j];
      if (v > bv) { bv = v; bp = j; }
    }
    #pragma unroll
    for (int off = 32; off >= 1; off >>= 1) {
      const float ov = __shfl_xor(bv, off);
      const int   op = __shfl_xor(bp, off);
      if (ov > bv || (ov == bv && ((unsigned)op < (unsigned)bp))) { bv = ov; bp = op; }
    }
    topv[r] = bv;
    int id = -2;
    if (bp >= 0 && bv > NEGF) id = (int)pdb[(size_t)ci[bp]*PDBW + CDIM];
    topid[r] = id;
    if (lane == 0 && bp >= 0) cv[bp] = NEGF;
    __syncthreads();
  }

  if (lane == 0) {
    bool mk[TK];
    int nvalid = 0;
    #pragma unroll
    for (int i = 0; i < TK; ++i) {
      mk[i] = (topv[i] >= MIN_SIM_C) && (topid[i] >= 0);
      nvalid += mk[i] ? 1 : 0;
    }
    int maj = 0, majid = 0x7fffffff;
    for (int i = 0; i < TK; ++i) {
      if (!mk[i]) continue;
      int c = 0;
      for (int j = 0; j < TK; ++j) c += (mk[j] && topid[j] == topid[i]) ? 1 : 0;
      if (c > maj || (c == maj && topid[i] < majid)) { maj = c; majid = topid[i]; }
    }
    const float ratio = (float)maj / fmaxf((float)nvalid, 1.0f);
    const bool valid = (maj > 0) && (ratio >= MIN_VOTES_C);
    const int label = valid ? majid : -1;
    float s = 0.f;
    #pragma unroll
    for (int i = 0; i < TK; ++i)
      if (mk[i] && topid[i] == label) s = fmaxf(s, topv[i]);
    out_label[q] = label;
    out_s[q]     = s;
  }
}

// ---------------------------------------------------------------------------
// Stage 3: overlap removal + final outputs
// ---------------------------------------------------------------------------
__device__ __forceinline__ bool finitef(float v) {
  return ((__float_as_uint(v) >> 23) & 0xffu) != 0xffu;
}

__global__ __launch_bounds__(64) void finalize_kernel(
    const float* __restrict__ boxes, const int* __restrict__ labels,
    const float* __restrict__ svals, float* __restrict__ out)
{
  const int x    = (int)blockIdx.x;
  const int lane = (int)threadIdx.x;
  const int lx = labels[x];
  const float bx1 = boxes[x*4+0], by1 = boxes[x*4+1];
  const float bx2 = boxes[x*4+2], by2 = boxes[x*4+3];
  const float ax = (bx2 - bx1) * (by2 - by1);

  bool flag = false;
  if (lx >= 0) {
    for (int y = lane; y < QN; y += 64) {
      if (y == x) continue;
      if (labels[y] != lx) continue;
      const float c1 = boxes[y*4+0], c2 = boxes[y*4+1];
      const float c3 = boxes[y*4+2], c4 = boxes[y*4+3];
      const float ay = (c3 - c1) * (c4 - c2);
      const float xi1 = fmaxf(bx1, c1), yi1 = fmaxf(by1, c2);
      const float xi2 = fminf(bx2, c3), yi2 = fminf(by2, c4);
      const float inter = fmaxf(xi2 - xi1, 0.f) * fmaxf(yi2 - yi1, 0.f);
      const float asmall = fminf(ax, ay);
      const float ov = (asmall > 0.f) ? inter / fmaxf(asmall, 1e-12f) : 0.f;
      if (ov >= 0.5f && ay <= ax) flag = true;
    }
  }
  const bool removed = (__ballot(flag) != 0ull);
  const int label = removed ? -1 : lx;
  const float s = svals[x];
  const bool fin = finitef(s) && finitef(bx1) && finitef(by1) && finitef(bx2) && finitef(by2);
  const bool valid = (label >= 0) && fin;

  if (lane == 0) {
    out[4096 + x] = valid ? s : 0.f;
    out[5120 + x] = (float)(valid ? label : -1);
  }
  if (lane < 4) out[x*4 + lane] = boxes[x*4 + lane];
}

// ---------------------------------------------------------------------------
extern "C" void kernel_launch(void* const* d_in, const int* in_sizes, int n_in,
                              void* d_out, int out_size, void* d_ws, size_t ws_size,
                              hipStream_t stream)
{
  const float* boxes = (const float*)d_in[0];
  const float* qd    = (const float*)d_in[1];
  const float* pdb   = (const float*)d_in[2];
  float* out = (float*)d_out;
  char* ws = (char*)d_ws;

  const size_t db_bytes  = (size_t)NDB_PAD * 256;             //  51,216,384 (fp8)
  const size_t seg_bytes = (size_t)QN * NCH * CAPQ * 8;       //  14,680,064
  const size_t cnt_bytes = (size_t)QN * NCH * 4;              //     524,288
  const size_t c1_bytes  = (size_t)QN * CPQ1 * 8;             //  12,845,056 (fallback, aliases seg+cnt)
  const size_t A_bytes   = (seg_bytes + cnt_bytes > c1_bytes) ? seg_bytes + cnt_bytes : c1_bytes;
  const size_t need = db_bytes + A_bytes + (size_t)QN*8 + 64;

  if (ws_size >= need) {
    unsigned char* dbb = (unsigned char*)ws;
    char* A = ws + db_bytes;
    unsigned long long* seg_g = (unsigned long long*)A;
    unsigned*           cnt_g = (unsigned*)(A + seg_bytes);
    float*    cand_val = (float*)A;
    unsigned* cand_idx = (unsigned*)(A + (size_t)QN*CPQ1*4);
    int*      labels   = (int*)(ws + db_bytes + A_bytes);
    float*    svals    = (float*)(ws + db_bytes + A_bytes + (size_t)QN*4);
    int*      flag     = (int*)(ws + db_bytes + A_bytes + (size_t)QN*8);

    hipMemsetAsync(flag, 0, 4, stream);
    hipLaunchKernelGGL(convert_db_kernel, dim3(2048), dim3(256), 0, stream, pdb, dbb);
    hipLaunchKernelGGL(sims_filter_kernel, dim3(NCH, 4), dim3(256), 0, stream,
                       qd, dbb, seg_g, cnt_g);
    hipLaunchKernelGGL(gather_vote_kernel, dim3(QN), dim3(64), 0, stream,
                       pdb, seg_g, cnt_g, labels, svals, flag);
    hipLaunchKernelGGL(sims_topk1_kernel, dim3(NCHUNK1, 8), dim3(256), 0, stream,
                       qd, pdb, cand_val, cand_idx, flag);
    hipLaunchKernelGGL((merge_vote_kernel<CPQ1>), dim3(QN), dim3(64), 0, stream,
                       pdb, cand_val, cand_idx, labels, svals, flag);
    hipLaunchKernelGGL(finalize_kernel, dim3(QN), dim3(64), 0, stream,
                       boxes, labels, svals, out);
  } else {
    const size_t n1 = (size_t)QN * CPQ1;
    float*    cand_val = (float*)ws;
    unsigned* cand_idx = (unsigned*)(ws + n1*4);
    int*      labels   = (int*)(ws + n1*8);
    float*    svals    = (float*)(ws + n1*8 + (size_t)QN*4);

    hipLaunchKernelGGL(sims_topk1_kernel, dim3(NCHUNK1, 8), dim3(256), 0, stream,
                       qd, pdb, cand_val, cand_idx, (const int*)nullptr);
    hipLaunchKernelGGL((merge_vote_kernel<CPQ1>), dim3(QN), dim3(64), 0, stream,
                       pdb, cand_val, cand_idx, labels, svals, (const int*)nullptr);
    hipLaunchKernelGGL(finalize_kernel, dim3(QN), dim3(64), 0, stream,
                       boxes, labels, svals, out);
  }
}

// Round 8
// 168.657 us; speedup vs baseline: 1.5183x; 1.0339x over previous
//
#include <hip/hip_runtime.h>
#include <hip/hip_bf16.h>

// ---------------- problem constants ----------------
#define QN 1024
#define NDB 200000
#define NDB_PAD 200064        // 3126 subtiles of 64 rows
#define PDBW 257
#define CDIM 256
#define TK 16
#define NEGF (-1e30f)
#define MIN_SIM_C 0.05f
#define MIN_VOTES_C 0.3f

// fast path: 128 chunks x 4 query-tiles (256 q/block, 4 waves); MX-fp8 filter
#define NCH 128
#define THETA 0.19f           // P(sim>THETA)=1.18e-3; true 16th-best ~0.236 (fp8 err ~3e-3 -> ~15 sigma)
#define CAPQ 14               // per-(query,chunk) cap (lambda~1.84, P(over)~1e-9/cell)
// fallback (round-1, proven) path
#define NCHUNK1 49
#define CPQ1 (NCHUNK1*32)

typedef __attribute__((ext_vector_type(8))) short bf16x8;
typedef __attribute__((ext_vector_type(4))) float f32x4;
typedef __attribute__((ext_vector_type(8))) int   i32x8;
typedef __attribute__((ext_vector_type(4))) int   i32x4;

__device__ __forceinline__ short f2bf(float f) {
  union { float f; unsigned u; } x; x.f = f;
  unsigned u = x.u;
  return (short)((u + 0x7fffu + ((u >> 16) & 1u)) >> 16);  // RNE
}

__device__ __forceinline__ void async_copy16(const void* gp, void* lp) {
  __builtin_amdgcn_global_load_lds(
      (__attribute__((address_space(1))) void*)gp,
      (__attribute__((address_space(3))) void*)lp, 16, 0, 0);
}

// pack 4 floats -> 4 fp8 e4m3 bytes (same converter feeds A and B, so any
// consistent lane-position->k mapping cancels in the MFMA dot product)
__device__ __forceinline__ unsigned pk_fp8x4(float a, float b, float c, float d) {
  unsigned w = (unsigned)__builtin_amdgcn_cvt_pk_fp8_f32(a, b, 0, false);
  w = (unsigned)__builtin_amdgcn_cvt_pk_fp8_f32(c, d, (int)w, true);
  return w;
}

// ---------------------------------------------------------------------------
// Kernel 0: pdb fp32 -> fp8 e4m3, 16B-pair swizzle (pair m -> m ^ (r&15)),
// zero-pad rows [NDB, NDB_PAD). Also zeroes the fallback flag (replaces the
// in-graph hipMemsetAsync dispatch).
// ---------------------------------------------------------------------------
__global__ __launch_bounds__(256) void convert_db_kernel(
    const float* __restrict__ pdb, unsigned char* __restrict__ dbb,
    int* __restrict__ flag)
{
  if (blockIdx.x == 0 && threadIdx.x == 0) *flag = 0;
  const int wv = (int)threadIdx.x >> 6, lane = (int)threadIdx.x & 63;
  for (int r = (int)blockIdx.x*4 + wv; r < NDB_PAD; r += (int)gridDim.x*4) {
    unsigned pack = 0u;
    if (r < NDB) {
      const float* p = pdb + (size_t)r*PDBW + lane*4;
      pack = pk_fp8x4(p[0], p[1], p[2], p[3]);
    }
    const int piece = lane >> 1;                       // 8B piece index 0..31
    const int ps    = piece ^ ((r & 15) << 1);         // == 16B-pair ^ (r&15)
    *(unsigned*)(dbb + (size_t)r*256 + ps*8 + (lane & 1)*4) = pack;
  }
}

// ---------------------------------------------------------------------------
// Kernel 1: MX-fp8 (K=128, unit scale) MFMA sims + register theta-filter +
// wave-private LDS survivor lists (flushed once after the loop).
// grid (128, 4), 256 thr (4 waves x 64 queries). Subtile = 64 db rows (16KB).
// TRIPLE-buffered LDS + counted vmcnt(4): every tile's DMA gets >=2 full
// iterations to land; the loop never drains vmcnt to 0 until the last tile.
// One barrier per subtile. 77KB LDS -> 2 independent blocks/CU.
// ---------------------------------------------------------------------------
__global__ __launch_bounds__(256, 2) void sims_filter_kernel(
    const float* __restrict__ qd, const unsigned char* __restrict__ dbb,
    unsigned long long* __restrict__ seg_g, unsigned int* __restrict__ cnt_g)
{
  __shared__ __align__(16) char db_lds[3][64 * 256];   // 3 x 16384 B (fp8)
  __shared__ unsigned seg_lds[4][64][CAPQ][2];         // 28672 B (wave-private)
  __shared__ int lcnt[4][64];                          // 1024 B (wave-private)

  const int tid  = (int)threadIdx.x;
  const int lane = tid & 63;
  const int wv   = tid >> 6;          // 0..3
  const int cid   = (int)blockIdx.x;  // 0..127
  const int mtile = (int)blockIdx.y;  // 0..3
  // chunks 0..53 have 25 subtiles, 54..127 have 24 (covers 3126 subtiles)
  const int nsub = 24 + (cid < 54 ? 1 : 0);
  const int row0 = (24*cid + (cid < 54 ? cid : 54)) << 6;

  lcnt[wv][lane] = 0;   // wave-private, no barrier needed

  const int l15  = lane & 15;
  const int egrp = lane >> 4;         // k-chunk group 0..3 (32 k each)
  const int rowb = egrp << 2;
  const int colb = l15;

  // ---- Q fragments: fp32 -> fp8 packed i32x8 (32 k-bytes/lane), per block ----
  i32x8 aq[4][2];
  {
    #pragma unroll
    for (int fm = 0; fm < 4; ++fm) {
      const float* qrow = qd + (size_t)(mtile*256 + wv*64 + fm*16 + l15)*CDIM;
      #pragma unroll
      for (int kk = 0; kk < 2; ++kk) {
        const float* p = qrow + kk*128 + egrp*32;
        i32x8 a;
        #pragma unroll
        for (int d = 0; d < 8; ++d) {
          float4 x = *(const float4*)(p + d*4);
          a[d] = (int)pk_fp8x4(x.x, x.y, x.z, x.w);
        }
        aq[fm][kk] = a;
      }
    }
  }

  const char* dbbase = (const char*)dbb;
#define STAGE(bufi, tile) do { \
    const char* _src = dbbase + ((size_t)(row0 + (tile)*64) * 256) + wv*4096 + lane*16; \
    char* _dst = (char*)db_lds[(bufi)] + wv*4096; \
    async_copy16(_src,        _dst); \
    async_copy16(_src + 1024, _dst + 1024); \
    async_copy16(_src + 2048, _dst + 2048); \
    async_copy16(_src + 3072, _dst + 3072); \
  } while (0)

  // prologue: 2 tiles in flight (8 loads/thread outstanding)
  STAGE(0, 0);
  STAGE(1, 1);

  int buf = 0;
  for (int s = 0; s < nsub; ++s) {
    // wait for tile s only; tile s+1 stays in flight (counted vmcnt -- the
    // loop never drains to 0 until the final tile)
    if (s + 1 < nsub) {
      asm volatile("s_waitcnt vmcnt(4)" ::: "memory");
    } else {
      asm volatile("s_waitcnt vmcnt(0)" ::: "memory");
    }
    __builtin_amdgcn_sched_barrier(0);
    __builtin_amdgcn_s_barrier();       // tile s resident for ALL waves; all
                                        // waves' tile-(s-1) reads are drained
    __builtin_amdgcn_sched_barrier(0);

    // stage tile s+2 into the buffer that held tile s-1 (safe: reads of s-1
    // finished before the barrier above); its DMA has ~2 iterations to land
    if (s + 2 < nsub) {
      const int b2 = (buf + 2 >= 3) ? buf - 1 : buf + 2;
      STAGE(b2, s + 2);
    }

    // ---- MFMA: 64q x 64db, K=256 via 2x K=128 MX-fp8 (unit scale) ----
    f32x4 acc[4][4];
    #pragma unroll
    for (int fm = 0; fm < 4; ++fm)
      #pragma unroll
      for (int fn = 0; fn < 4; ++fn)
        acc[fm][fn] = (f32x4){0.f, 0.f, 0.f, 0.f};
    __builtin_amdgcn_s_setprio(1);
    {
      const char* dbt = (const char*)db_lds[buf];
      #pragma unroll
      for (int kk = 0; kk < 2; ++kk) {
        #pragma unroll
        for (int fn = 0; fn < 4; ++fn) {
          const char* rowp = dbt + (fn*16 + l15)*256;
          const int mbase = kk*8 + egrp*2;
          i32x4 lo = *(const i32x4*)(rowp + (((mbase    ) ^ l15) << 4));
          i32x4 hi = *(const i32x4*)(rowp + (((mbase + 1) ^ l15) << 4));
          i32x8 b = __builtin_shufflevector(lo, hi, 0, 1, 2, 3, 4, 5, 6, 7);
          #pragma unroll
          for (int fm = 0; fm < 4; ++fm)
            acc[fm][fn] = __builtin_amdgcn_mfma_scale_f32_16x16x128_f8f6f4(
                aq[fm][kk], b, acc[fm][fn],
                0 /*fmtA=fp8*/, 0 /*fmtB=fp8*/,
                0, 0x7F7F7F7Fu /*scaleA=1.0*/, 0, 0x7F7F7F7Fu /*scaleB=1.0*/);
        }
      }
    }
    __builtin_amdgcn_s_setprio(0);

    // ---- theta-filter on fragments; wave-private LDS append (lgkm domain,
    //      never touches the vmem prefetch queue) ----
    {
      const int idxbase = row0 + s*64;
      #pragma unroll
      for (int fm = 0; fm < 4; ++fm)
        #pragma unroll
        for (int fn = 0; fn < 4; ++fn) {
          const f32x4 a = acc[fm][fn];
          const float m = fmaxf(fmaxf(a[0], a[1]), fmaxf(a[2], a[3]));
          if (m > THETA) {
            #pragma unroll
            for (int j = 0; j < 4; ++j) {
              if (a[j] > THETA) {
                const int ql = fm*16 + rowb + j;
                const int slot = atomicAdd(&lcnt[wv][ql], 1);
                if (slot < CAPQ) {
                  seg_lds[wv][ql][slot][0] = __float_as_uint(a[j]);
                  seg_lds[wv][ql][slot][1] = (unsigned)(idxbase + fn*16 + colb);
                }
              }
            }
          }
        }
    }

    // drain own ds_reads + LDS ops before the next barrier (this is what
    // makes the single-barrier buffer-rotation hazard-free)
    asm volatile("s_waitcnt lgkmcnt(0)" ::: "memory");
    __builtin_amdgcn_sched_barrier(0);
    buf = (buf + 1 >= 3) ? 0 : buf + 1;
  }
#undef STAGE

  // ---- flush wave-private survivor lists to global (lane == local query) ----
  {
    const int cnt = lcnt[wv][lane];
    const int qg = mtile*256 + wv*64 + lane;
    cnt_g[qg*NCH + cid] = (unsigned)cnt;
    const int nc = min(cnt, CAPQ);
    unsigned long long* dst = seg_g + (size_t)(qg*NCH + cid)*CAPQ;
    for (int j = 0; j < nc; ++j) {
      unsigned long long lo = seg_lds[wv][lane][j][0];
      unsigned long long hi = seg_lds[wv][lane][j][1];
      dst[j] = lo | (hi << 32);
    }
  }
}

// ---------------------------------------------------------------------------
// Kernel 2: per-query gather of survivors -> exact top-16 -> vote.
// Self-check: overflow or <16 survivors -> set flag (triggers fallback).
// ---------------------------------------------------------------------------
__global__ __launch_bounds__(64) void gather_vote_kernel(
    const float* __restrict__ pdb,
    const unsigned long long* __restrict__ seg_g, const unsigned* __restrict__ cnt_g,
    int* __restrict__ out_label, float* __restrict__ out_s, int* __restrict__ flag)
{
  __shared__ float    cv[NCH*CAPQ];   // 1792
  __shared__ unsigned ci[NCH*CAPQ];
  const int q    = (int)blockIdx.x;
  const int lane = (int)threadIdx.x;

  bool over = false;
  int tot = 0;
  #pragma unroll
  for (int h = 0; h < 2; ++h) {
    const int c = h*64 + lane;
    const int cnt = (int)cnt_g[q*NCH + c];
    over |= (cnt > CAPQ);
    const int nc = min(cnt, CAPQ);
    tot += nc;
    const unsigned long long* src = seg_g + (size_t)(q*NCH + c)*CAPQ;
    for (int j = 0; j < CAPQ; ++j) {
      float v = NEGF; unsigned idx = 0u;
      if (j < nc) {
        const unsigned long long e = src[j];
        v = __uint_as_float((unsigned)e);
        idx = (unsigned)(e >> 32);
      }
      cv[c*CAPQ + j] = v;
      ci[c*CAPQ + j] = idx;
    }
  }
  #pragma unroll
  for (int off = 32; off >= 1; off >>= 1) tot += __shfl_xor(tot, off);
  __syncthreads();

  float topv[TK]; int topid[TK];
  #pragma unroll
  for (int r = 0; r < TK; ++r) {
    float bv = NEGF; int bp = -1;
    #pragma unroll 4
    for (int j = 0; j < (NCH*CAPQ)/64; ++j) {
      const int p = j*64 + lane;
      const float v = cv[p];
      if (v > bv) { bv = v; bp = p; }
    }
    #pragma unroll
    for (int off = 32; off >= 1; off >>= 1) {
      const float ov = __shfl_xor(bv, off);
      const int   op = __shfl_xor(bp, off);
      if (ov > bv || (ov == bv && ((unsigned)op < (unsigned)bp))) { bv = ov; bp = op; }
    }
    topv[r] = bv;
    int id = -2;
    if (bp >= 0 && bv > NEGF) id = (int)pdb[(size_t)ci[bp]*PDBW + CDIM];
    topid[r] = id;
    if (lane == 0 && bp >= 0) cv[bp] = NEGF;
    __syncthreads();
  }

  if (lane == 0) {
    bool mk[TK];
    int nvalid = 0;
    #pragma unroll
    for (int i = 0; i < TK; ++i) {
      mk[i] = (topv[i] >= MIN_SIM_C) && (topid[i] >= 0);
      nvalid += mk[i] ? 1 : 0;
    }
    int maj = 0, majid = 0x7fffffff;
    for (int i = 0; i < TK; ++i) {
      if (!mk[i]) continue;
      int c = 0;
      for (int j = 0; j < TK; ++j) c += (mk[j] && topid[j] == topid[i]) ? 1 : 0;
      if (c > maj || (c == maj && topid[i] < majid)) { maj = c; majid = topid[i]; }
    }
    const float ratio = (float)maj / fmaxf((float)nvalid, 1.0f);
    const bool valid = (maj > 0) && (ratio >= MIN_VOTES_C);
    const int label = valid ? majid : -1;
    float s = 0.f;
    #pragma unroll
    for (int i = 0; i < TK; ++i)
      if (mk[i] && topid[i] == label) s = fmaxf(s, topv[i]);
    out_label[q] = label;
    out_s[q]     = s;
  }
  const bool bad = (__ballot(over) != 0ull) || (tot < TK);
  if (lane == 0 && bad) atomicOr(flag, 1);
}

// ---------------------------------------------------------------------------
// Fallback stage 1 (round-1, proven): gated on flag
// ---------------------------------------------------------------------------
__global__ __launch_bounds__(256, 2) void sims_topk1_kernel(
    const float* __restrict__ qd, const float* __restrict__ pdb,
    float* __restrict__ cand_val, unsigned int* __restrict__ cand_idx,
    const int* __restrict__ gate)
{
  if (gate && *gate == 0) return;
  __shared__ __align__(16) short db_lds[128 * 264];
  float* sims = (float*)db_lds;

  const int tid  = (int)threadIdx.x;
  const int lane = tid & 63;
  const int wv   = tid >> 6;
  const int cid   = (int)blockIdx.x;
  const int mtile = (int)blockIdx.y;

  bf16x8 aq[2][8];
  {
    const int l15 = lane & 15;
    const int kb  = (lane >> 4) << 3;
    #pragma unroll
    for (int fm = 0; fm < 2; ++fm) {
      const int row = mtile*128 + wv*32 + fm*16 + l15;
      #pragma unroll
      for (int kk = 0; kk < 8; ++kk) {
        const float* p = qd + (size_t)row*CDIM + kk*32 + kb;
        float4 x0 = *(const float4*)p;
        float4 x1 = *(const float4*)(p + 4);
        bf16x8 a;
        a[0]=f2bf(x0.x); a[1]=f2bf(x0.y); a[2]=f2bf(x0.z); a[3]=f2bf(x0.w);
        a[4]=f2bf(x1.x); a[5]=f2bf(x1.y); a[6]=f2bf(x1.z); a[7]=f2bf(x1.w);
        aq[fm][kk] = a;
      }
    }
  }

  float    tv[TK];
  unsigned ti[TK];
  #pragma unroll
  for (int i = 0; i < TK; ++i) { tv[i] = NEGF; ti[i] = 0u; }
  float minv = NEGF; int minp = 0;

  const int g0chunk = cid * 4096;
  const int q_l  = tid & 127;
  const int half = tid >> 7;

  for (int s = 0; s < 32; ++s) {
    const int g0 = g0chunk + s*128;
    {
      const int rb = tid >> 6;
      const int c4 = (tid & 63) << 2;
      for (int i = 0; i < 32; ++i) {
        const int rl = i*4 + rb;
        const int g  = g0 + rl;
        float v0, v1, v2, v3;
        if (g < NDB) {
          const float* p = pdb + (size_t)g*PDBW + c4;
          v0 = p[0]; v1 = p[1]; v2 = p[2]; v3 = p[3];
        } else { v0 = v1 = v2 = v3 = 0.f; }
        short* d = &db_lds[rl*264 + c4];
        d[0]=f2bf(v0); d[1]=f2bf(v1); d[2]=f2bf(v2); d[3]=f2bf(v3);
      }
    }
    __syncthreads();

    f32x4 acc[2][8];
    #pragma unroll
    for (int fm = 0; fm < 2; ++fm)
      #pragma unroll
      for (int fn = 0; fn < 8; ++fn)
        acc[fm][fn] = (f32x4){0.f, 0.f, 0.f, 0.f};
    {
      const int l15 = lane & 15;
      const int kb  = (lane >> 4) << 3;
      #pragma unroll
      for (int kk = 0; kk < 8; ++kk) {
        bf16x8 b[8];
        #pragma unroll
        for (int fn = 0; fn < 8; ++fn)
          b[fn] = *(const bf16x8*)&db_lds[(fn*16 + l15)*264 + kk*32 + kb];
        #pragma unroll
        for (int fn = 0; fn < 8; ++fn) {
          acc[0][fn] = __builtin_amdgcn_mfma_f32_16x16x32_bf16(aq[0][kk], b[fn], acc[0][fn], 0, 0, 0);
          acc[1][fn] = __builtin_amdgcn_mfma_f32_16x16x32_bf16(aq[1][kk], b[fn], acc[1][fn], 0, 0, 0);
        }
      }
    }
    __syncthreads();

    {
      const int colb = lane & 15;
      const int rowb = (lane >> 4) << 2;
      #pragma unroll
      for (int fm = 0; fm < 2; ++fm)
        #pragma unroll
        for (int fn = 0; fn < 8; ++fn)
          #pragma unroll
          for (int j = 0; j < 4; ++j)
            sims[(wv*32 + fm*16 + rowb + j)*129 + fn*16 + colb] = acc[fm][fn][j];
    }
    __syncthreads();

    {
      const int cb = half * 64;
      #pragma unroll 4
      for (int c = 0; c < 64; ++c) {
        const int colc = cb + c;
        const float v = sims[q_l*129 + colc];
        const int g = g0 + colc;
        if (v > minv && g < NDB) {
          #pragma unroll
          for (int i = 0; i < TK; ++i) if (i == minp) { tv[i] = v; ti[i] = (unsigned)g; }
          minv = tv[0]; minp = 0;
          #pragma unroll
          for (int i = 1; i < TK; ++i) if (tv[i] < minv) { minv = tv[i]; minp = i; }
        }
      }
    }
    __syncthreads();
  }

  {
    const int qg = mtile*128 + q_l;
    float*    pv = cand_val + ((size_t)qg*NCHUNK1 + cid)*32 + half*TK;
    unsigned* pi = cand_idx + ((size_t)qg*NCHUNK1 + cid)*32 + half*TK;
    #pragma unroll
    for (int i = 0; i < TK; ++i) { pv[i] = tv[i]; pi[i] = ti[i]; }
  }
}

// ---------------------------------------------------------------------------
// Fallback stage 2 (round-1, proven): gated on flag
// ---------------------------------------------------------------------------
template<int CPQ>
__global__ __launch_bounds__(64) void merge_vote_kernel(
    const float* __restrict__ pdb,
    const float* __restrict__ cand_val, const unsigned* __restrict__ cand_idx,
    int* __restrict__ out_label, float* __restrict__ out_s,
    const int* __restrict__ gate)
{
  if (gate && *gate == 0) return;
  __shared__ float    cv[CPQ];
  __shared__ unsigned ci[CPQ];
  const int q    = (int)blockIdx.x;
  const int lane = (int)threadIdx.x;

  for (int j = lane; j < CPQ; j += 64) {
    cv[j] = cand_val[(size_t)q*CPQ + j];
    ci[j] = cand_idx[(size_t)q*CPQ + j];
  }
  __syncthreads();

  float topv[TK]; int topid[TK];
  #pragma unroll
  for (int r = 0; r < TK; ++r) {
    float bv = NEGF; int bp = -1;
    for (int j = lane; j < CPQ; j += 64) {
      const float v = cv[j];
      if (v > bv) { bv = v; bp = j; }
    }
    #pragma unroll
    for (int off = 32; off >= 1; off >>= 1) {
      const float ov = __shfl_xor(bv, off);
      const int   op = __shfl_xor(bp, off);
      if (ov > bv || (ov == bv && ((unsigned)op < (unsigned)bp))) { bv = ov; bp = op; }
    }
    topv[r] = bv;
    int id = -2;
    if (bp >= 0 && bv > NEGF) id = (int)pdb[(size_t)ci[bp]*PDBW + CDIM];
    topid[r] = id;
    if (lane == 0 && bp >= 0) cv[bp] = NEGF;
    __syncthreads();
  }

  if (lane == 0) {
    bool mk[TK];
    int nvalid = 0;
    #pragma unroll
    for (int i = 0; i < TK; ++i) {
      mk[i] = (topv[i] >= MIN_SIM_C) && (topid[i] >= 0);
      nvalid += mk[i] ? 1 : 0;
    }
    int maj = 0, majid = 0x7fffffff;
    for (int i = 0; i < TK; ++i) {
      if (!mk[i]) continue;
      int c = 0;
      for (int j = 0; j < TK; ++j) c += (mk[j] && topid[j] == topid[i]) ? 1 : 0;
      if (c > maj || (c == maj && topid[i] < majid)) { maj = c; majid = topid[i]; }
    }
    const float ratio = (float)maj / fmaxf((float)nvalid, 1.0f);
    const bool valid = (maj > 0) && (ratio >= MIN_VOTES_C);
    const int label = valid ? majid : -1;
    float s = 0.f;
    #pragma unroll
    for (int i = 0; i < TK; ++i)
      if (mk[i] && topid[i] == label) s = fmaxf(s, topv[i]);
    out_label[q] = label;
    out_s[q]     = s;
  }
}

// ---------------------------------------------------------------------------
// Stage 3: overlap removal + final outputs
// ---------------------------------------------------------------------------
__device__ __forceinline__ bool finitef(float v) {
  return ((__float_as_uint(v) >> 23) & 0xffu) != 0xffu;
}

__global__ __launch_bounds__(64) void finalize_kernel(
    const float* __restrict__ boxes, const int* __restrict__ labels,
    const float* __restrict__ svals, float* __restrict__ out)
{
  const int x    = (int)blockIdx.x;
  const int lane = (int)threadIdx.x;
  const int lx = labels[x];
  const float bx1 = boxes[x*4+0], by1 = boxes[x*4+1];
  const float bx2 = boxes[x*4+2], by2 = boxes[x*4+3];
  const float ax = (bx2 - bx1) * (by2 - by1);

  bool flag = false;
  if (lx >= 0) {
    for (int y = lane; y < QN; y += 64) {
      if (y == x) continue;
      if (labels[y] != lx) continue;
      const float c1 = boxes[y*4+0], c2 = boxes[y*4+1];
      const float c3 = boxes[y*4+2], c4 = boxes[y*4+3];
      const float ay = (c3 - c1) * (c4 - c2);
      const float xi1 = fmaxf(bx1, c1), yi1 = fmaxf(by1, c2);
      const float xi2 = fminf(bx2, c3), yi2 = fminf(by2, c4);
      const float inter = fmaxf(xi2 - xi1, 0.f) * fmaxf(yi2 - yi1, 0.f);
      const float asmall = fminf(ax, ay);
      const float ov = (asmall > 0.f) ? inter / fmaxf(asmall, 1e-12f) : 0.f;
      if (ov >= 0.5f && ay <= ax) flag = true;
    }
  }
  const bool removed = (__ballot(flag) != 0ull);
  const int label = removed ? -1 : lx;
  const float s = svals[x];
  const bool fin = finitef(s) && finitef(bx1) && finitef(by1) && finitef(bx2) && finitef(by2);
  const bool valid = (label >= 0) && fin;

  if (lane == 0) {
    out[4096 + x] = valid ? s : 0.f;
    out[5120 + x] = (float)(valid ? label : -1);
  }
  if (lane < 4) out[x*4 + lane] = boxes[x*4 + lane];
}

// ---------------------------------------------------------------------------
extern "C" void kernel_launch(void* const* d_in, const int* in_sizes, int n_in,
                              void* d_out, int out_size, void* d_ws, size_t ws_size,
                              hipStream_t stream)
{
  const float* boxes = (const float*)d_in[0];
  const float* qd    = (const float*)d_in[1];
  const float* pdb   = (const float*)d_in[2];
  float* out = (float*)d_out;
  char* ws = (char*)d_ws;

  const size_t db_bytes  = (size_t)NDB_PAD * 256;             //  51,216,384 (fp8)
  const size_t seg_bytes = (size_t)QN * NCH * CAPQ * 8;       //  14,680,064
  const size_t cnt_bytes = (size_t)QN * NCH * 4;              //     524,288
  const size_t c1_bytes  = (size_t)QN * CPQ1 * 8;             //  12,845,056 (fallback, aliases seg+cnt)
  const size_t A_bytes   = (seg_bytes + cnt_bytes > c1_bytes) ? seg_bytes + cnt_bytes : c1_bytes;
  const size_t need = db_bytes + A_bytes + (size_t)QN*8 + 64;

  if (ws_size >= need) {
    unsigned char* dbb = (unsigned char*)ws;
    char* A = ws + db_bytes;
    unsigned long long* seg_g = (unsigned long long*)A;
    unsigned*           cnt_g = (unsigned*)(A + seg_bytes);
    float*    cand_val = (float*)A;
    unsigned* cand_idx = (unsigned*)(A + (size_t)QN*CPQ1*4);
    int*      labels   = (int*)(ws + db_bytes + A_bytes);
    float*    svals    = (float*)(ws + db_bytes + A_bytes + (size_t)QN*4);
    int*      flag     = (int*)(ws + db_bytes + A_bytes + (size_t)QN*8);

    hipLaunchKernelGGL(convert_db_kernel, dim3(2048), dim3(256), 0, stream, pdb, dbb, flag);
    hipLaunchKernelGGL(sims_filter_kernel, dim3(NCH, 4), dim3(256), 0, stream,
                       qd, dbb, seg_g, cnt_g);
    hipLaunchKernelGGL(gather_vote_kernel, dim3(QN), dim3(64), 0, stream,
                       pdb, seg_g, cnt_g, labels, svals, flag);
    hipLaunchKernelGGL(sims_topk1_kernel, dim3(NCHUNK1, 8), dim3(256), 0, stream,
                       qd, pdb, cand_val, cand_idx, flag);
    hipLaunchKernelGGL((merge_vote_kernel<CPQ1>), dim3(QN), dim3(64), 0, stream,
                       pdb, cand_val, cand_idx, labels, svals, flag);
    hipLaunchKernelGGL(finalize_kernel, dim3(QN), dim3(64), 0, stream,
                       boxes, labels, svals, out);
  } else {
    const size_t n1 = (size_t)QN * CPQ1;
    float*    cand_val = (float*)ws;
    unsigned* cand_idx = (unsigned*)(ws + n1*4);
    int*      labels   = (int*)(ws + n1*8);
    float*    svals    = (float*)(ws + n1*8 + (size_t)QN*4);

    hipLaunchKernelGGL(sims_topk1_kernel, dim3(NCHUNK1, 8), dim3(256), 0, stream,
                       qd, pdb, cand_val, cand_idx, (const int*)nullptr);
    hipLaunchKernelGGL((merge_vote_kernel<CPQ1>), dim3(QN), dim3(64), 0, stream,
                       pdb, cand_val, cand_idx, labels, svals, (const int*)nullptr);
    hipLaunchKernelGGL(finalize_kernel, dim3(QN), dim3(64), 0, stream,
                       boxes, labels, svals, out);
  }
}